// Round 9
// baseline (761.637 us; speedup 1.0000x reference)
//
#include <hip/hip_runtime.h>

typedef short    bf16x8 __attribute__((ext_vector_type(8)));
typedef float    f32x4  __attribute__((ext_vector_type(4)));
typedef unsigned short u16x8 __attribute__((ext_vector_type(8)));

__device__ __forceinline__ unsigned short f2bf(float f) {
    unsigned u = __float_as_uint(f);
    return (unsigned short)((u + 0x7fffu + ((u >> 16) & 1u)) >> 16);
}
__device__ __forceinline__ float bf2f(unsigned short h) {
    return __uint_as_float((unsigned)h << 16);
}

template<bool> struct otype            { using T = float; };
template<>     struct otype<true>      { using T = unsigned short; };

// ---------------------------------------------------------------------------
// Generic tiled fp32 GEMM (fallback path only).
// ---------------------------------------------------------------------------
template<int BM,int BN,int TM,int TN,bool BT,bool VA,bool VB,bool OB>
__launch_bounds__(256)
__global__ void gemm_f32(const float* __restrict__ A, int lda, long long sA,
                         const float* __restrict__ B, int ldb, long long sB,
                         void* __restrict__ Cv, int ldc, long long sC,
                         int M, int N, int K,
                         const float* __restrict__ bias,
                         const float* __restrict__ mul, int mulld)
{
    constexpr int BK  = 16;
    constexpr int GSA = BM*4/TM;
    constexpr int GSB = BN*4/TN;
    __shared__ float As[BK][BM+4];
    __shared__ float Bs[BK][BN+4];

    const int bz = blockIdx.z;
    A += (long long)bz * sA;
    B += (long long)bz * sB;
    using OT = typename otype<OB>::T;
    OT* C = (OT*)Cv + (long long)bz * sC;
    const int m0 = blockIdx.y * BM;
    const int n0 = blockIdx.x * BN;
    const int tid = threadIdx.x;
    const int tm = tid >> 4;
    const int tn = tid & 15;

    float acc[TM][TN];
#pragma unroll
    for (int i=0;i<TM;++i)
#pragma unroll
        for (int j=0;j<TN;++j) acc[i][j]=0.f;

    for (int k0=0;k0<K;k0+=BK) {
        if constexpr (VA) {
#pragma unroll
            for (int r=0;r<BM*BK/1024;++r) {
                int v = tid + r*256;
                int m = v >> 2, k4 = (v & 3)*4;
                int gm = m0+m, gk = k0+k4;
                float4 val = make_float4(0.f,0.f,0.f,0.f);
                if (gm < M) {
                    if (gk+3 < K) {
                        val = *reinterpret_cast<const float4*>(A + (long long)gm*lda + gk);
                    } else {
                        float t0 = (gk   < K) ? A[(long long)gm*lda+gk  ] : 0.f;
                        float t1 = (gk+1 < K) ? A[(long long)gm*lda+gk+1] : 0.f;
                        float t2 = (gk+2 < K) ? A[(long long)gm*lda+gk+2] : 0.f;
                        val = make_float4(t0,t1,t2,0.f);
                    }
                }
                As[k4+0][m]=val.x; As[k4+1][m]=val.y; As[k4+2][m]=val.z; As[k4+3][m]=val.w;
            }
        } else {
#pragma unroll
            for (int r=0;r<BM*BK/256;++r) {
                int e = tid + r*256;
                int m = e >> 4, k = e & 15;
                int gm=m0+m, gk=k0+k;
                As[k][m] = (gm<M && gk<K) ? A[(long long)gm*lda+gk] : 0.f;
            }
        }
        if constexpr (!BT) {
            if constexpr (VB) {
#pragma unroll
                for (int r=0;r<BK*BN/1024;++r) {
                    int v = tid + r*256;
                    int k = v / (BN/4), n4 = (v % (BN/4))*4;
                    int gk=k0+k, gn=n0+n4;
                    float4 val = make_float4(0.f,0.f,0.f,0.f);
                    if (gk < K) {
                        if (gn+3 < N) {
                            val = *reinterpret_cast<const float4*>(B + (long long)gk*ldb + gn);
                        } else {
                            float t0=(gn  <N)?B[(long long)gk*ldb+gn  ]:0.f;
                            float t1=(gn+1<N)?B[(long long)gk*ldb+gn+1]:0.f;
                            float t2=(gn+2<N)?B[(long long)gk*ldb+gn+2]:0.f;
                            val = make_float4(t0,t1,t2,0.f);
                        }
                    }
                    Bs[k][n4+0]=val.x; Bs[k][n4+1]=val.y; Bs[k][n4+2]=val.z; Bs[k][n4+3]=val.w;
                }
            } else {
#pragma unroll
                for (int r=0;r<BK*BN/256;++r) {
                    int e = tid + r*256;
                    int k = e / BN, n = e % BN;
                    int gk=k0+k, gn=n0+n;
                    Bs[k][n] = (gk<K && gn<N) ? B[(long long)gk*ldb+gn] : 0.f;
                }
            }
        } else {
            if constexpr (VB) {
#pragma unroll
                for (int r=0;r<BN*BK/1024;++r) {
                    int v = tid + r*256;
                    int n = v >> 2, k4 = (v&3)*4;
                    int gn=n0+n, gk=k0+k4;
                    float4 val = make_float4(0.f,0.f,0.f,0.f);
                    if (gn < N) {
                        if (gk+3 < K) {
                            val = *reinterpret_cast<const float4*>(B + (long long)gn*ldb + gk);
                        } else {
                            float t0=(gk  <K)?B[(long long)gn*ldb+gk  ]:0.f;
                            float t1=(gk+1<K)?B[(long long)gn*ldb+gk+1]:0.f;
                            float t2=(gk+2<K)?B[(long long)gn*ldb+gk+2]:0.f;
                            val=make_float4(t0,t1,t2,0.f);
                        }
                    }
                    Bs[k4+0][n]=val.x; Bs[k4+1][n]=val.y; Bs[k4+2][n]=val.z; Bs[k4+3][n]=val.w;
                }
            } else {
#pragma unroll
                for (int r=0;r<BN*BK/256;++r) {
                    int e = tid + r*256;
                    int n = e >> 4, k = e & 15;
                    int gn=n0+n, gk=k0+k;
                    Bs[k][n] = (gn<N && gk<K) ? B[(long long)gn*ldb+gk] : 0.f;
                }
            }
        }
        __syncthreads();
#pragma unroll
        for (int kk=0;kk<BK;++kk) {
            float a[TM], bb[TN];
#pragma unroll
            for (int g=0;g<TM/4;++g) {
                float4 t = *reinterpret_cast<const float4*>(&As[kk][g*GSA + tm*4]);
                a[4*g+0]=t.x; a[4*g+1]=t.y; a[4*g+2]=t.z; a[4*g+3]=t.w;
            }
#pragma unroll
            for (int g=0;g<TN/4;++g) {
                float4 t = *reinterpret_cast<const float4*>(&Bs[kk][g*GSB + tn*4]);
                bb[4*g+0]=t.x; bb[4*g+1]=t.y; bb[4*g+2]=t.z; bb[4*g+3]=t.w;
            }
#pragma unroll
            for (int i=0;i<TM;++i)
#pragma unroll
                for (int j=0;j<TN;++j)
                    acc[i][j] = fmaf(a[i], bb[j], acc[i][j]);
        }
        __syncthreads();
    }
#pragma unroll
    for (int i=0;i<TM;++i) {
        int row = m0 + (i>>2)*GSA + tm*4 + (i&3);
        if (row < M) {
#pragma unroll
            for (int j=0;j<TN;++j) {
                int col = n0 + (j>>2)*GSB + tn*4 + (j&3);
                if (col < N) {
                    float val = acc[i][j];
                    if (bias) val += bias[col];
                    if (mul)  val *= mul[(long long)row*mulld + col];
                    if constexpr (OB) C[(long long)row*ldc + col] = f2bf(val);
                    else              C[(long long)row*ldc + col] = val;
                }
            }
        }
    }
}

// ---------------------------------------------------------------------------
// Pipelined bf16 MFMA GEMM, B^T form: base = sum_k A[m,k]*Bt[n,k].
// BM=128, BN=256, BK=32, 512 thr = 8 waves (2x4), wave tile 64x64.
// Ring of 3 LDS buffers, counted vmcnt; T2 swizzle; XCD-bijective remap.
// Epilogue flags F: 1=BIAS 2=MUL(f32) 128=MULB(bf16) 4=OB(bf16, LDS-staged
//   coalesced store) 8=OT(bf16 transposed; +32 applies AFF first)
//   16=EXPM1 (x=exp(acc)-1 -> bf16 LDS-staged coalesced store + per-row
//             partial sums of stored-bf16 x -> partial[])
//   32=AFF   (val=(acc+hsum[bz*Ncols+col])*invs[bz*M+row], fp32 out)
//   64=A2W   (nx==0 blocks ALSO write a2out[row][k]=(1+x)*invs[row] fp32
//             from the staged A-tile in the K-loop; invalid lanes -> dump)
// ---------------------------------------------------------------------------
template<unsigned F>
__launch_bounds__(512, 4)
__global__ void gemm_mfma_p(const unsigned short* __restrict__ A, int lda, long long sA,
                            const unsigned short* __restrict__ Bt, int ldb, long long sB,
                            void* __restrict__ Cv, int ldc, long long sC,
                            int M, int Ncols, int NX, int NY, int NT,
                            const float* __restrict__ bias,
                            const float* __restrict__ mul, int ldm,
                            float* __restrict__ partial, long long pstride,
                            const float* __restrict__ hsum,
                            const float* __restrict__ invs,
                            float* __restrict__ a2out,
                            float* __restrict__ dump)
{
    __shared__ unsigned short lds[3][12288];    // 72KB ring; reused as 64KB epilogue tile

    // bijective XCD-chunked remap (m204 formula)
    const int nwg = gridDim.x;
    const int q = nwg >> 3, r = nwg & 7;
    const int xcd = blockIdx.x & 7, idx = blockIdx.x >> 3;
    const int wg = (xcd < r ? xcd*(q+1) : r*(q+1) + (xcd-r)*q) + idx;
    const int nx = wg % NX;
    const int t1 = wg / NX;
    const int my = t1 % NY;
    const int bz = t1 / NY;

    const int tid  = threadIdx.x;
    const int lane = tid & 63, wid = tid >> 6;
    const int wr = wid >> 2, wc = wid & 3;
    const int fr = lane & 15, fq = lane >> 4;
    const int m0 = my * 128;
    const int n0 = nx * 256;

    A  += (long long)bz * sA;
    Bt += (long long)bz * sB;

    const int srow = tid >> 2;
    const int scz  = (tid & 3) ^ ((srow >> 1) & 3);
    long long arow = m0 + srow; if (arow > M-1) arow = M-1;
    const unsigned short* aSrc  = A  + arow*lda + scz*8;
    const unsigned short* bSrc0 = Bt + (long long)(n0 + srow)*ldb + scz*8;
    const unsigned short* bSrc1 = bSrc0 + 128ll*ldb;

    // A2W setup (before pipeline so the invs load drains here, not in-loop)
    bool wrblk = false, a2ok = false;
    float invv = 0.f;
    float* a2p = nullptr;
    if constexpr ((F & 64) != 0) {
        wrblk = (nx == 0);
        if (wrblk) {
            const int rrow = m0 + srow;
            a2ok = rrow < M;
            const long long ridx = (long long)bz*M + (a2ok ? rrow : M-1);
            invv = invs[ridx];
            asm volatile("" : "+v"(invv));   // materialize: load-wait lands HERE
            a2p = a2out + ridx*2000ll;
        }
    }

    int aoff[4], boff[4];
#pragma unroll
    for (int m=0;m<4;++m) {
        const int ra = wr*64 + m*16 + fr;
        aoff[m] = ra*64 + ((fq ^ ((ra>>1)&3))*16);
    }
#pragma unroll
    for (int n=0;n<4;++n) {
        const int rb = wc*64 + n*16 + fr;
        boff[n] = 8192 + rb*64 + ((fq ^ ((rb>>1)&3))*16);
    }

    f32x4 acc[4][4];
#pragma unroll
    for (int i=0;i<4;++i)
#pragma unroll
        for (int j=0;j<4;++j) acc[i][j] = (f32x4)(0.f);

    auto stage = [&](int s, int t) {
        const int koff = t*32;
        char* base = (char*)&lds[s][0];
        __builtin_amdgcn_global_load_lds(
            (const __attribute__((address_space(1))) void*)(aSrc + koff),
            (__attribute__((address_space(3))) void*)(base + tid*16), 16, 0, 0);
        __builtin_amdgcn_global_load_lds(
            (const __attribute__((address_space(1))) void*)(bSrc0 + koff),
            (__attribute__((address_space(3))) void*)(base + 8192 + tid*16), 16, 0, 0);
        __builtin_amdgcn_global_load_lds(
            (const __attribute__((address_space(1))) void*)(bSrc1 + koff),
            (__attribute__((address_space(3))) void*)(base + 16384 + tid*16), 16, 0, 0);
    };

    stage(0, 0);
    stage(1, NT > 1 ? 1 : 0);
    asm volatile("s_waitcnt vmcnt(3)" ::: "memory");
    __builtin_amdgcn_s_barrier();

    int cur = 0, stg = 2;
    for (int kt = 0; kt < NT; ++kt) {
        int tnx = kt + 2; if (tnx > NT-1) tnx = NT-1;   // uniform issue count
        stage(stg, tnx);
        const char* bp = (const char*)&lds[cur][0];
        bf16x8 a[4], b[4];
#pragma unroll
        for (int m=0;m<4;++m) a[m] = *(const bf16x8*)(bp + aoff[m]);
#pragma unroll
        for (int n=0;n<4;++n) b[n] = *(const bf16x8*)(bp + boff[n]);
        __builtin_amdgcn_s_setprio(1);
#pragma unroll
        for (int m=0;m<4;++m)
#pragma unroll
            for (int n=0;n<4;++n)
                acc[m][n] = __builtin_amdgcn_mfma_f32_16x16x32_bf16(a[m], b[n], acc[m][n], 0, 0, 0);
        __builtin_amdgcn_s_setprio(0);
        if constexpr ((F & 64) != 0) {
            if (wrblk) {
                u16x8 av = *(const u16x8*)(bp + (tid << 4));
                const int col0 = kt*32 + scz*8;
                const bool ok = a2ok && (col0 < 2000);
                float* p0 = ok ? (a2p + col0) : (dump + (tid << 3));
                float4 o0, o1;
                o0.x = fmaf(bf2f((unsigned short)av[0]), invv, invv);
                o0.y = fmaf(bf2f((unsigned short)av[1]), invv, invv);
                o0.z = fmaf(bf2f((unsigned short)av[2]), invv, invv);
                o0.w = fmaf(bf2f((unsigned short)av[3]), invv, invv);
                o1.x = fmaf(bf2f((unsigned short)av[4]), invv, invv);
                o1.y = fmaf(bf2f((unsigned short)av[5]), invv, invv);
                o1.z = fmaf(bf2f((unsigned short)av[6]), invv, invv);
                o1.w = fmaf(bf2f((unsigned short)av[7]), invv, invv);
                *(float4*)(p0    ) = o0;
                *(float4*)(p0 + 4) = o1;
            }
        }
        asm volatile("s_waitcnt lgkmcnt(0)" ::: "memory");
        if constexpr ((F & 64) != 0) {
            if (wrblk) asm volatile("s_waitcnt vmcnt(5)" ::: "memory");
            else       asm volatile("s_waitcnt vmcnt(3)" ::: "memory");
        } else {
            asm volatile("s_waitcnt vmcnt(3)" ::: "memory");
        }
        __builtin_amdgcn_s_barrier();
        cur = (cur == 2) ? 0 : cur + 1;
        stg = (stg == 2) ? 0 : stg + 1;
    }

    // ---- epilogues (C/D layout: col = lane&15, row = (lane>>4)*4 + j) ----
    if constexpr ((F & 16) != 0) {
        asm volatile("s_waitcnt vmcnt(0)" ::: "memory");
        __builtin_amdgcn_s_barrier();
        unsigned short* ep = (unsigned short*)&lds[0][0];
        unsigned short* Cb = (unsigned short*)Cv + (long long)bz * sC;
#pragma unroll
        for (int m=0;m<4;++m) {
            const int rl = wr*64 + m*16 + fq*4;
#pragma unroll
            for (int n=0;n<4;++n) {
                const int cl = wc*64 + n*16 + fr;
                const int cb = cl*2;
#pragma unroll
                for (int j=0;j<4;++j) {
                    const int row = rl + j;
                    float x = __expf(acc[m][n][j]) - 1.0f;
                    const int ch = (cb>>5) ^ ((row>>2)&3);
                    *(unsigned short*)((char*)ep + row*512 + (ch<<5) + (cb&31)) = f2bf(x);
                }
            }
        }
        __syncthreads();
        const int rq = tid >> 3;
        const int cq = tid & 7;
#pragma unroll
        for (int half=0; half<2; ++half) {
            const int row = rq + half*64;
            const int grow = m0 + row;
            float s = 0.f;
#pragma unroll
            for (int win=0; win<4; ++win) {
                const int cb = cq*16 + win*128;
                const int ch = (cb>>5) ^ ((row>>2)&3);
                u16x8 v = *(const u16x8*)((const char*)ep + row*512 + (ch<<5) + (cb&31));
#pragma unroll
                for (int i=0;i<8;++i) s += bf2f((unsigned short)v[i]);
                if (grow < M) *(u16x8*)(Cb + (long long)grow*ldc + n0 + (cb>>1)) = v;
            }
            s += __shfl_xor(s, 1); s += __shfl_xor(s, 2); s += __shfl_xor(s, 4);
            if (cq == 0 && grow < M)
                partial[(long long)nx*pstride + (long long)bz*M + grow] = s;
        }
    } else if constexpr ((F & 8) != 0) {
        unsigned short* Ct = (unsigned short*)Cv + (long long)bz * sC;
#pragma unroll
        for (int m=0;m<4;++m) {
            const int rb = m0 + wr*64 + m*16 + fq*4;
#pragma unroll
            for (int n=0;n<4;++n) {
                const int col = n0 + wc*64 + n*16 + fr;
                if (col < Ncols) {
                    float hv = 0.f;
                    if constexpr ((F & 32) != 0) hv = hsum[(long long)bz*Ncols + col];
#pragma unroll
                    for (int j=0;j<4;++j) {
                        const int row = rb + j;
                        float val = 0.f;
                        if (row < M) {
                            val = acc[m][n][j];
                            if constexpr ((F & 32) != 0) val = (val + hv) * invs[(long long)bz*M + row];
                        }
                        Ct[(long long)col*ldc + row] = f2bf(val);
                    }
                }
            }
        }
    } else if constexpr ((F & 4) != 0) {
        asm volatile("s_waitcnt vmcnt(0)" ::: "memory");
        __builtin_amdgcn_s_barrier();
        unsigned short* ep = (unsigned short*)&lds[0][0];
        unsigned short* Cb = (unsigned short*)Cv + (long long)bz * sC;
#pragma unroll
        for (int m=0;m<4;++m) {
            const int rl = wr*64 + m*16 + fq*4;
#pragma unroll
            for (int n=0;n<4;++n) {
                const int cl = wc*64 + n*16 + fr;
                const int gcol = n0 + cl;
                const int cb = cl*2;
                float bv = 0.f;
                if constexpr ((F & 1) != 0) bv = bias[gcol];
#pragma unroll
                for (int j=0;j<4;++j) {
                    const int row = rl + j;
                    float val = acc[m][n][j];
                    if constexpr ((F & 1) != 0) val += bv;
                    if constexpr ((F & 128) != 0) {
                        int mr = m0 + row; if (mr > M-1) mr = M-1;
                        val *= bf2f(((const unsigned short*)mul)[(long long)mr*ldm + gcol]);
                    }
                    if constexpr ((F & 2) != 0) {
                        int mr = m0 + row; if (mr > M-1) mr = M-1;
                        val *= mul[(long long)mr*ldm + gcol];
                    }
                    const int ch = (cb>>5) ^ ((row>>2)&3);
                    *(unsigned short*)((char*)ep + row*512 + (ch<<5) + (cb&31)) = f2bf(val);
                }
            }
        }
        __syncthreads();
        const int rq = tid >> 3;
        const int cq = tid & 7;
#pragma unroll
        for (int half=0; half<2; ++half) {
            const int row = rq + half*64;
            const int grow = m0 + row;
#pragma unroll
            for (int win=0; win<4; ++win) {
                const int cb = cq*16 + win*128;
                const int ch = (cb>>5) ^ ((row>>2)&3);
                u16x8 v = *(const u16x8*)((const char*)ep + row*512 + (ch<<5) + (cb&31));
                const int gc = n0 + (cb>>1);
                if (grow < M && gc < Ncols) *(u16x8*)(Cb + (long long)grow*ldc + gc) = v;
            }
        }
    } else {
        float* Cf = (float*)Cv + (long long)bz * sC;
#pragma unroll
        for (int m=0;m<4;++m) {
            const int rb = m0 + wr*64 + m*16 + fq*4;
#pragma unroll
            for (int n=0;n<4;++n) {
                const int col = n0 + wc*64 + n*16 + fr;
                if (col < Ncols) {
                    float bv = 0.f, hv = 0.f;
                    if constexpr ((F & 1) != 0) bv = bias[col];
                    if constexpr ((F & 32) != 0) hv = hsum[(long long)bz*Ncols + col];
#pragma unroll
                    for (int j=0;j<4;++j) {
                        const int row = rb + j;
                        if (row < M) {
                            float val = acc[m][n][j];
                            if constexpr ((F & 1)   != 0) val += bv;
                            if constexpr ((F & 2)   != 0) val *= mul[(long long)row*ldm + col];
                            if constexpr ((F & 128) != 0) val *= bf2f(((const unsigned short*)mul)[(long long)row*ldm + col]);
                            if constexpr ((F & 32)  != 0) val = (val + hv) * invs[(long long)bz*M + row];
                            Cf[(long long)row*ldc + col] = val;
                        }
                    }
                }
            }
        }
    }
}

// ---------------------------------------------------------------------------
// High-intensity pipelined MFMA GEMM (EXPM1 epilogue only):
// BM=256, BN=128, BK=32, 256 thr = 4 waves (2M x 2N), wave tile 128x64,
// acc[8][4] (42.7 FLOP per LDS byte vs 32 in gemm_mfma_p). Same ring-3
// counted-vmcnt structure, counts per formula: 6 loads/stage -> vmcnt(6).
// Slot = A 16KB + B 8KB = 24KB; ring 72KB -> 2 blocks/CU.
// Output: x = expm1(acc) -> bf16 (LDS-staged coalesced), row partials.
// Caller guarantees Bt rows [0,NX*128) and cols [0,NT*32) readable; A rows
// clamped to M-1; output rows masked to < M.
// ---------------------------------------------------------------------------
__launch_bounds__(256, 2)
__global__ void gemm_mfma_q(const unsigned short* __restrict__ A, int lda, long long sA,
                            const unsigned short* __restrict__ Bt, int ldb, long long sB,
                            unsigned short* __restrict__ Cb0, int ldc, long long sC,
                            int M, int NX, int NY, int NT,
                            float* __restrict__ partial, long long pstride)
{
    __shared__ unsigned short lds[3][12288];    // 3 x 24KB; epilogue reuses 64KB

    const int nwg = gridDim.x;
    const int q = nwg >> 3, r = nwg & 7;
    const int xcd = blockIdx.x & 7, idx = blockIdx.x >> 3;
    const int wg = (xcd < r ? xcd*(q+1) : r*(q+1) + (xcd-r)*q) + idx;
    const int nx = wg % NX;
    const int t1 = wg / NX;
    const int my = t1 % NY;
    const int bz = t1 / NY;

    const int tid  = threadIdx.x;
    const int lane = tid & 63, wid = tid >> 6;  // 4 waves
    const int wr = wid >> 1, wcn = wid & 1;     // wave grid 2M x 2N
    const int fr = lane & 15, fq = lane >> 4;
    const int m0 = my * 256;
    const int n0 = nx * 128;

    A  += (long long)bz * sA;
    Bt += (long long)bz * sB;

    // staging: 6 issues of 256thr x 16B (A rows 0-255 in 4, B rows 0-127 in 2)
    const int t64 = tid >> 2;                       // row within issue
    const int scz = (tid & 3) ^ ((tid >> 3) & 3);   // issue-invariant swizzle key
    const unsigned short* aS[4];
#pragma unroll
    for (int i=0;i<4;++i) {
        long long ar = m0 + i*64 + t64; if (ar > M-1) ar = M-1;
        aS[i] = A + ar*lda + scz*8;
    }
    const unsigned short* bS[2];
#pragma unroll
    for (int i=0;i<2;++i)
        bS[i] = Bt + (long long)(n0 + i*64 + t64)*ldb + scz*8;

    int aoff[8], boff[4];
#pragma unroll
    for (int m=0;m<8;++m) {
        const int ra = wr*128 + m*16 + fr;
        aoff[m] = ra*64 + ((fq ^ ((ra>>1)&3))*16);
    }
#pragma unroll
    for (int n=0;n<4;++n) {
        const int rb = wcn*64 + n*16 + fr;
        boff[n] = 16384 + rb*64 + ((fq ^ ((rb>>1)&3))*16);
    }

    f32x4 acc[8][4];
#pragma unroll
    for (int i=0;i<8;++i)
#pragma unroll
        for (int j=0;j<4;++j) acc[i][j] = (f32x4)(0.f);

    auto stage = [&](int s, int t) {
        const int koff = t*32;
        char* base = (char*)&lds[s][0];
#pragma unroll
        for (int i=0;i<4;++i)
            __builtin_amdgcn_global_load_lds(
                (const __attribute__((address_space(1))) void*)(aS[i] + koff),
                (__attribute__((address_space(3))) void*)(base + i*4096 + tid*16), 16, 0, 0);
#pragma unroll
        for (int i=0;i<2;++i)
            __builtin_amdgcn_global_load_lds(
                (const __attribute__((address_space(1))) void*)(bS[i] + koff),
                (__attribute__((address_space(3))) void*)(base + 16384 + i*4096 + tid*16), 16, 0, 0);
    };

    stage(0, 0);
    stage(1, NT > 1 ? 1 : 0);
    asm volatile("s_waitcnt vmcnt(6)" ::: "memory");   // tile 0 landed
    __builtin_amdgcn_s_barrier();

    int cur = 0, stg = 2;
    for (int kt = 0; kt < NT; ++kt) {
        int tnx = kt + 2; if (tnx > NT-1) tnx = NT-1;
        stage(stg, tnx);
        const char* bp = (const char*)&lds[cur][0];
        bf16x8 a[8], b[4];
#pragma unroll
        for (int m=0;m<8;++m) a[m] = *(const bf16x8*)(bp + aoff[m]);
#pragma unroll
        for (int n=0;n<4;++n) b[n] = *(const bf16x8*)(bp + boff[n]);
        __builtin_amdgcn_s_setprio(1);
#pragma unroll
        for (int m=0;m<8;++m)
#pragma unroll
            for (int n=0;n<4;++n)
                acc[m][n] = __builtin_amdgcn_mfma_f32_16x16x32_bf16(a[m], b[n], acc[m][n], 0, 0, 0);
        __builtin_amdgcn_s_setprio(0);
        asm volatile("s_waitcnt lgkmcnt(0)" ::: "memory");
        asm volatile("s_waitcnt vmcnt(6)" ::: "memory");   // tile kt+1 landed
        __builtin_amdgcn_s_barrier();
        cur = (cur == 2) ? 0 : cur + 1;
        stg = (stg == 2) ? 0 : stg + 1;
    }

    // ---- EXPM1 epilogue: LDS-staged coalesced store (256 rows x 256B) ----
    asm volatile("s_waitcnt vmcnt(0)" ::: "memory");   // drain tail stages
    __builtin_amdgcn_s_barrier();
    unsigned short* ep = (unsigned short*)&lds[0][0];
    unsigned short* Cb = Cb0 + (long long)bz * sC;
#pragma unroll
    for (int m=0;m<8;++m) {
        const int rl = wr*128 + m*16 + fq*4;
#pragma unroll
        for (int n=0;n<4;++n) {
            const int cl = wcn*64 + n*16 + fr;
            const int cb = cl*2;                     // byte col 0..255
#pragma unroll
            for (int j=0;j<4;++j) {
                const int row = rl + j;
                float x = __expf(acc[m][n][j]) - 1.0f;
                const int ch = (cb>>5) ^ ((row>>2)&7);
                *(unsigned short*)((char*)ep + row*256 + (ch<<5) + (cb&31)) = f2bf(x);
            }
        }
    }
    __syncthreads();
    const int rq = tid >> 3;        // 32 rows per pass, 8 thr/row -> 128B windows
    const int cq = tid & 7;
#pragma unroll
    for (int pass=0; pass<8; ++pass) {
        const int row = rq + pass*32;
        const int grow = m0 + row;
        float s = 0.f;
#pragma unroll
        for (int win=0; win<2; ++win) {
            const int cb = cq*16 + win*128;
            const int ch = (cb>>5) ^ ((row>>2)&7);
            u16x8 v = *(const u16x8*)((const char*)ep + row*256 + (ch<<5) + (cb&31));
#pragma unroll
            for (int i=0;i<8;++i) s += bf2f((unsigned short)v[i]);
            if (grow < M) *(u16x8*)(Cb + (long long)grow*ldc + n0 + (cb>>1)) = v;
        }
        s += __shfl_xor(s, 1); s += __shfl_xor(s, 2); s += __shfl_xor(s, 4);
        if (cq == 0 && grow < M)
            partial[(long long)nx*pstride + (long long)bz*M + grow] = s;
    }
}

// ---------------------------------------------------------------------------
// 2-phase MFMA GEMM (tier-2 fallback C2, fp32 A on the fly).
// ---------------------------------------------------------------------------
template<bool AF32>
__launch_bounds__(512, 2)
__global__ void gemm_mfma(const void* __restrict__ Ain, int lda, long long sA,
                          const unsigned short* __restrict__ Bt, int ldb, long long sB,
                          float* __restrict__ C, int ldc, long long sC,
                          int M, int N, int K, int NT)
{
    __shared__ unsigned short As[2][128*32];
    __shared__ unsigned short Bs[2][256*32];

    const int tid  = threadIdx.x;
    const int lane = tid & 63, wid = tid >> 6;
    const int wr = wid >> 2, wc = wid & 3;
    const int fr = lane & 15, fq = lane >> 4;
    const int bz = blockIdx.z;
    const int m0 = blockIdx.y * 128;
    const int n0 = blockIdx.x * 256;

    const unsigned short* Ab = nullptr;
    const float*          Af = nullptr;
    if constexpr (AF32) Af = (const float*)Ain + (long long)bz * sA;
    else                Ab = (const unsigned short*)Ain + (long long)bz * sA;
    Bt += (long long)bz * sB;
    C  += (long long)bz * sC;

    const int srow = tid >> 2;
    const int sc   = tid & 3;
    const int scz  = sc ^ ((srow >> 1) & 3);
    int arow = m0 + srow; if (arow > M-1) arow = M-1;
    const bool am_ok = (m0 + srow) < M;
    const long long brow0 = n0 + srow;
    const long long brow1 = n0 + 128 + srow;
    const int ldsA  = wid << 10;
    const int ldsB0 = wid << 10;
    const int ldsB1 = 8192 + (wid << 10);

    f32x4 acc[4][4];
#pragma unroll
    for (int i=0;i<4;++i)
#pragma unroll
        for (int j=0;j<4;++j) acc[i][j] = (f32x4)(0.f);

    auto stage = [&](int buf, int t) {
        const long long koff = (long long)t * 32;
        __builtin_amdgcn_global_load_lds(
            (const __attribute__((address_space(1))) void*)(Bt + brow0*ldb + koff + scz*8),
            (__attribute__((address_space(3))) void*)((char*)&Bs[buf][0] + ldsB0), 16, 0, 0);
        __builtin_amdgcn_global_load_lds(
            (const __attribute__((address_space(1))) void*)(Bt + brow1*ldb + koff + scz*8),
            (__attribute__((address_space(3))) void*)((char*)&Bs[buf][0] + ldsB1), 16, 0, 0);
        if constexpr (!AF32) {
            __builtin_amdgcn_global_load_lds(
                (const __attribute__((address_space(1))) void*)(Ab + (long long)arow*lda + koff + scz*8),
                (__attribute__((address_space(3))) void*)((char*)&As[buf][0] + ldsA), 16, 0, 0);
        } else {
            const float* src = Af + (long long)arow*lda + koff + scz*8;
            const int kk = t*32 + scz*8;
            float4 z = make_float4(0.f,0.f,0.f,0.f);
            float4 v0 = (am_ok && kk   < K) ? *(const float4*)(src  ) : z;
            float4 v1 = (am_ok && kk+4 < K) ? *(const float4*)(src+4) : z;
            u16x8 o;
            o[0]=f2bf(v0.x); o[1]=f2bf(v0.y); o[2]=f2bf(v0.z); o[3]=f2bf(v0.w);
            o[4]=f2bf(v1.x); o[5]=f2bf(v1.y); o[6]=f2bf(v1.z); o[7]=f2bf(v1.w);
            *(u16x8*)((char*)&As[buf][0] + tid*16) = o;
        }
    };

    stage(0, 0);
    int cur = 0;
    for (int t = 0; t < NT; ++t) {
        __syncthreads();
        if (t + 1 < NT) stage(cur ^ 1, t + 1);
        const unsigned short* as = As[cur];
        const unsigned short* bs = Bs[cur];
        bf16x8 a[4], b[4];
#pragma unroll
        for (int m=0;m<4;++m) {
            const int ra = wr*64 + m*16 + fr;
            a[m] = *(const bf16x8*)(as + ra*32 + (fq ^ ((ra>>1)&3))*8);
        }
#pragma unroll
        for (int n=0;n<4;++n) {
            const int rb = wc*64 + n*16 + fr;
            b[n] = *(const bf16x8*)(bs + rb*32 + (fq ^ ((rb>>1)&3))*8);
        }
        __builtin_amdgcn_s_setprio(1);
#pragma unroll
        for (int m=0;m<4;++m)
#pragma unroll
            for (int n=0;n<4;++n)
                acc[m][n] = __builtin_amdgcn_mfma_f32_16x16x32_bf16(a[m], b[n], acc[m][n], 0, 0, 0);
        __builtin_amdgcn_s_setprio(0);
        cur ^= 1;
    }
#pragma unroll
    for (int m=0;m<4;++m) {
        const int rb = m0 + wr*64 + m*16 + fq*4;
#pragma unroll
        for (int n=0;n<4;++n) {
            const int col = n0 + wc*64 + n*16 + fr;
            if (col < N) {
#pragma unroll
                for (int j=0;j<4;++j) {
                    const int row = rb + j;
                    if (row < M) C[(long long)row*ldc + col] = acc[m][n][j];
                }
            }
        }
    }
}

// ---------------------------------------------------------------------------
// mega_prep: ONE launch doing all input prep.
// ---------------------------------------------------------------------------
__global__ __launch_bounds__(256) void mega_prep(const float* __restrict__ H,
                                                 unsigned short* __restrict__ Hb,
                                                 unsigned short* __restrict__ Htb,
                                                 float* __restrict__ hpart,
                                                 const float* __restrict__ Wmap,  unsigned short* __restrict__ Wb,
                                                 const float* __restrict__ Q1w,   unsigned short* __restrict__ Q1wb,
                                                 const float* __restrict__ Q2w,   unsigned short* __restrict__ Q2wb,
                                                 const float* __restrict__ Q12w,  unsigned short* __restrict__ Q12wb)
{
    __shared__ unsigned short T[64][80];
    const int tid = threadIdx.x;
    int id = blockIdx.x;
    if (id < 2048) {
        const int lt = id & 31;
        const int dt = (id >> 5) & 7;
        const int bz = id >> 8;
        const int d0 = dt * 64;
        const int l0 = lt * 64;
        const float* Hsrc = H + ((long long)bz*512 + d0) * 2000;
        const int dl = tid >> 2;
        const int lc = (tid & 3) * 16;
        float4 v[4];
        float s = 0.f;
#pragma unroll
        for (int i=0;i<4;++i) {
            const int gl = l0 + lc + i*4;
            v[i] = make_float4(0.f,0.f,0.f,0.f);
            if (gl < 2000) v[i] = *(const float4*)(Hsrc + (long long)dl*2000 + gl);
            s += (v[i].x + v[i].y) + (v[i].z + v[i].w);
            T[lc+i*4+0][dl] = f2bf(v[i].x);
            T[lc+i*4+1][dl] = f2bf(v[i].y);
            T[lc+i*4+2][dl] = f2bf(v[i].z);
            T[lc+i*4+3][dl] = f2bf(v[i].w);
        }
        {
            unsigned short* hb = Hb + ((long long)bz*512 + d0 + dl)*2048 + l0 + lc;
            u16x8 h0, h1;
            h0[0]=f2bf(v[0].x); h0[1]=f2bf(v[0].y); h0[2]=f2bf(v[0].z); h0[3]=f2bf(v[0].w);
            h0[4]=f2bf(v[1].x); h0[5]=f2bf(v[1].y); h0[6]=f2bf(v[1].z); h0[7]=f2bf(v[1].w);
            h1[0]=f2bf(v[2].x); h1[1]=f2bf(v[2].y); h1[2]=f2bf(v[2].z); h1[3]=f2bf(v[2].w);
            h1[4]=f2bf(v[3].x); h1[5]=f2bf(v[3].y); h1[6]=f2bf(v[3].z); h1[7]=f2bf(v[3].w);
            *(u16x8*)(hb    ) = h0;
            *(u16x8*)(hb + 8) = h1;
        }
        s += __shfl_xor(s, 1);
        s += __shfl_xor(s, 2);
        if ((tid & 3) == 0)
            hpart[(long long)lt*4096 + bz*512 + d0 + dl] = s;
        __syncthreads();
        unsigned short* Hdst = Htb + ((long long)bz*2048 + l0) * 512 + d0;
        const int ll = tid >> 2;
        const int dc = (tid & 3) * 16;
        u16x8 w0 = *(const u16x8*)&T[ll][dc];
        u16x8 w1 = *(const u16x8*)&T[ll][dc+8];
        *(u16x8*)(Hdst + (long long)ll*512 + dc    ) = w0;
        *(u16x8*)(Hdst + (long long)ll*512 + dc + 8) = w1;
        return;
    }
    id -= 2048;
    if (id < 640) {
        const int i = id*256 + tid;
        if (i < 512*320) {
            const int r2 = i/320, c = i - r2*320;
            Wb[i] = (c < 300) ? f2bf(Wmap[r2*300 + c]) : (unsigned short)0;
        }
    } else if (id < 788) {
        const int i = (id-640)*256 + tid;
        if (i < 118*320) {
            const int r2 = i/320, c = i - r2*320;
            Q1wb[i] = (c < 300) ? f2bf(Q1w[r2*300 + c]) : (unsigned short)0;
        }
    } else if (id < 11950) {
        const int i = (id-788)*256 + tid;
        if (i < 8929*320) {
            const int r2 = i/320, c = i - r2*320;
            Q2wb[i] = (c < 300) ? f2bf(Q2w[r2*300 + c]) : (unsigned short)0;
        }
    } else {
        const int i = (id-11950)*256 + tid;
        if (i < 8929*128) {
            const int r2 = i >> 7, c = i & 127;
            Q12wb[i] = (c < 118) ? f2bf(Q12w[r2*118 + c]) : (unsigned short)0;
        }
    }
}

// Hsum[r] = sum_{i<32} hpart[i][r],  r < 4096
__global__ __launch_bounds__(256) void reduce_hsum(const float* __restrict__ hpart,
                                                   float* __restrict__ Hsum)
{
    const int r = blockIdx.x*256 + threadIdx.x;
    float s = 0.f;
#pragma unroll
    for (int i=0;i<32;++i) s += hpart[(long long)i*4096 + r];
    Hsum[r] = s;
}

// invs[r] = 1 / (2000 + sum_{i<cnt} partial[i][r]),  r < n
__global__ __launch_bounds__(256) void invs_k(const float* __restrict__ partial,
                                              long long pstride,
                                              float* __restrict__ invs, int n, int cnt)
{
    const int r = blockIdx.x*256 + threadIdx.x;
    if (r < n) {
        float s = 0.f;
        for (int i=0;i<cnt;++i) s += partial[i*pstride + r];
        invs[r] = 1.0f / (2000.0f + s);
    }
}

// ---------------------------------------------------------------------------
// fallback-only kernels
// ---------------------------------------------------------------------------
__global__ __launch_bounds__(256) void cvt_pad_bf16(const float* __restrict__ H,
                                                    unsigned short* __restrict__ Hb)
{
    const long long idx = (long long)blockIdx.x * 256 + threadIdx.x;
    const long long row = idx >> 8;
    const int l0 = (int)(idx & 255) * 8;
    u16x8 o = (u16x8)(unsigned short)0;
    if (l0 + 8 <= 2000) {
        const float* s = H + row*2000 + l0;
        float4 v0 = *(const float4*)(s);
        float4 v1 = *(const float4*)(s+4);
        o[0]=f2bf(v0.x); o[1]=f2bf(v0.y); o[2]=f2bf(v0.z); o[3]=f2bf(v0.w);
        o[4]=f2bf(v1.x); o[5]=f2bf(v1.y); o[6]=f2bf(v1.z); o[7]=f2bf(v1.w);
    }
    *(u16x8*)(Hb + row*2048 + l0) = o;
}

__global__ __launch_bounds__(256) void cvt_transpose_bf16(const float* __restrict__ H,
                                                          unsigned short* __restrict__ Ht)
{
    __shared__ unsigned short T[64][80];
    const int bz = blockIdx.z;
    const int d0 = blockIdx.y * 64;
    const int l0 = blockIdx.x * 64;
    const float* Hsrc = H + ((long long)bz*512 + d0) * 2000;
    unsigned short* Hdst = Ht + ((long long)bz*2048 + l0) * 512 + d0;
    const int tid = threadIdx.x;
    const int dl = tid >> 2;
    const int lc = (tid & 3) * 16;
#pragma unroll
    for (int i=0;i<4;++i) {
        const int l = lc + i*4;
        const int gl = l0 + l;
        float4 v = make_float4(0.f,0.f,0.f,0.f);
        if (gl < 2000) v = *(const float4*)(Hsrc + (long long)dl*2000 + gl);
        T[l+0][dl] = f2bf(v.x);
        T[l+1][dl] = f2bf(v.y);
        T[l+2][dl] = f2bf(v.z);
        T[l+3][dl] = f2bf(v.w);
    }
    __syncthreads();
    const int ll = tid >> 2;
    const int dc = (tid & 3) * 16;
    u16x8 w0 = *(const u16x8*)&T[ll][dc];
    u16x8 w1 = *(const u16x8*)&T[ll][dc+8];
    *(u16x8*)(Hdst + (long long)ll*512 + dc    ) = w0;
    *(u16x8*)(Hdst + (long long)ll*512 + dc + 8) = w1;
}

__global__ __launch_bounds__(256) void softmax_rows(float* __restrict__ X, int L,
                                                    unsigned short* __restrict__ Xb, int Lb)
{
    const long long row = blockIdx.x;
    float* x = X + row * (long long)L;
    const int tid = threadIdx.x;
    const int nv = L >> 2;
    const bool h0 = tid < nv;
    const bool h1 = tid + 256 < nv;
    float4 t0 = make_float4(0.f,0.f,0.f,0.f);
    float4 t1 = make_float4(0.f,0.f,0.f,0.f);
    float mx = -3.402823e38f;
    if (h0) { t0 = *reinterpret_cast<const float4*>(x + 4*tid);
              mx = fmaxf(fmaxf(t0.x,t0.y), fmaxf(t0.z,t0.w)); }
    if (h1) { t1 = *reinterpret_cast<const float4*>(x + 4*(tid+256));
              mx = fmaxf(mx, fmaxf(fmaxf(t1.x,t1.y), fmaxf(t1.z,t1.w))); }
    __shared__ float sred[4];
#pragma unroll
    for (int o=32;o;o>>=1) mx = fmaxf(mx, __shfl_xor(mx, o));
    if ((tid & 63)==0) sred[tid>>6] = mx;
    __syncthreads();
    mx = fmaxf(fmaxf(sred[0],sred[1]), fmaxf(sred[2],sred[3]));
    __syncthreads();
    float s = 0.f;
    if (h0) {
        t0.x=__expf(t0.x-mx); t0.y=__expf(t0.y-mx); t0.z=__expf(t0.z-mx); t0.w=__expf(t0.w-mx);
        s += (t0.x+t0.y)+(t0.z+t0.w);
    }
    if (h1) {
        t1.x=__expf(t1.x-mx); t1.y=__expf(t1.y-mx); t1.z=__expf(t1.z-mx); t1.w=__expf(t1.w-mx);
        s += (t1.x+t1.y)+(t1.z+t1.w);
    }
#pragma unroll
    for (int o=32;o;o>>=1) s += __shfl_xor(s, o);
    if ((tid & 63)==0) sred[tid>>6] = s;
    __syncthreads();
    s = (sred[0]+sred[1])+(sred[2]+sred[3]);
    const float inv = 1.0f / s;
    if (h0) { t0.x*=inv; t0.y*=inv; t0.z*=inv; t0.w*=inv;
              *reinterpret_cast<float4*>(x + 4*tid) = t0; }
    if (h1) { t1.x*=inv; t1.y*=inv; t1.z*=inv; t1.w*=inv;
              *reinterpret_cast<float4*>(x + 4*(tid+256)) = t1; }
    if (Xb) {
        unsigned short* xb = Xb + row * (long long)Lb;
        if (h0) {
            ushort4 o; o.x=f2bf(t0.x); o.y=f2bf(t0.y); o.z=f2bf(t0.z); o.w=f2bf(t0.w);
            *reinterpret_cast<ushort4*>(xb + 4*tid) = o;
        }
        if (h1) {
            ushort4 o; o.x=f2bf(t1.x); o.y=f2bf(t1.y); o.z=f2bf(t1.z); o.w=f2bf(t1.w);
            *reinterpret_cast<ushort4*>(xb + 4*(tid+256)) = o;
        }
        if (tid < (Lb - L)/4) {
            ushort4 z; z.x=z.y=z.z=z.w=0;
            *reinterpret_cast<ushort4*>(xb + L + 4*tid) = z;
        }
    }
}

// ---------------------------------------------------------------------------
extern "C" void kernel_launch(void* const* d_in, const int* in_sizes, int n_in,
                              void* d_out, int out_size, void* d_ws, size_t ws_size,
                              hipStream_t stream)
{
    const float* H    = (const float*)d_in[0];  // [8,512,2000]
    const float* Q1w  = (const float*)d_in[1];  // [118,300]
    const float* Q2w  = (const float*)d_in[2];  // [8929,300]
    const float* Q12w = (const float*)d_in[3];  // [8929,118]
    const float* Wmap = (const float*)d_in[4];  // [512,300]
    const float* bmap = (const float*)d_in[5];  // [512]

    constexpr long long B=8, D=512, L=2000, N1=118, N2=8929;
    constexpr long long C2E = B*N2*D;
    float* out = (float*)d_out;
    float* C2  = out;            // [8,8929,512]
    float* A2  = out + C2E;      // [8,8929,2000]

    dim3 blk(256);

    // workspace layout (256B-aligned slots)
    size_t off = 0;
    auto alloc = [&](size_t n)->size_t { off = (off + 255) & ~(size_t)255; size_t o = off; off += n; return o; };
    const size_t oHb    = alloc(8ll*512*2048*2);
    const size_t oHtb   = alloc(8ll*2048*512*2);
    const size_t oWb    = alloc(512ll*320*2);
    const size_t oQ1wb  = alloc(118ll*320*2);
    const size_t oQ2wb  = alloc(8929ll*320*2);
    const size_t oQ12wb = alloc(8929ll*128*2);
    const size_t oQ1b   = alloc(118ll*512*2);
    const size_t oEmbb  = alloc(8929ll*512*2);
    const size_t oE1x   = alloc(8ll*128*2048*2);
    const size_t oC1tb  = alloc(8ll*512*128*2);
    const size_t oQ2b   = alloc(8ll*8929*512*2);
    const size_t oA2b   = alloc(8ll*8929*2048*2);
    const size_t oPart  = alloc(16ll*8*8929*4);    // NX=16 slices (q-kernel)
    const size_t oPart1 = alloc(16ll*944*4);       // NX=16 slices (q-kernel)
    const size_t oInvs  = alloc(8ll*8929*4);
    const size_t oInvs1 = alloc(944ll*4);
    const size_t oHsum  = alloc(8ll*512*4);
    const size_t oHpart = alloc(32ll*4096*4);
    const size_t FULL_NEED = off;

    char* ws = (char*)d_ws;

    if (ws_size >= FULL_NEED) {
        unsigned short* Hb    = (unsigned short*)(ws + oHb);
        unsigned short* Htb   = (unsigned short*)(ws + oHtb);
        unsigned short* Wb    = (unsigned short*)(ws + oWb);
        unsigned short* Q1wb  = (unsigned short*)(ws + oQ1wb);
        unsigned short* Q2wb  = (unsigned short*)(ws + oQ2wb);
        unsigned short* Q12wb = (unsigned short*)(ws + oQ12wb);
        unsigned short* Q1b   = (unsigned short*)(ws + oQ1b);
        unsigned short* Embb  = (unsigned short*)(ws + oEmbb);
        unsigned short* E1x   = (unsigned short*)(ws + oE1x);
        unsigned short* C1tb  = (unsigned short*)(ws + oC1tb);
        unsigned short* Q2b   = (unsigned short*)(ws + oQ2b);
        unsigned short* A2b   = (unsigned short*)(ws + oA2b);
        float*          part  = (float*)(ws + oPart);
        float*          part1 = (float*)(ws + oPart1);
        float*          invs  = (float*)(ws + oInvs);
        float*          invs1 = (float*)(ws + oInvs1);
        float*          Hsum  = (float*)(ws + oHsum);
        float*          hpart = (float*)(ws + oHpart);

        // 0. all input prep in ONE launch
        mega_prep<<<dim3(18464), blk, 0, stream>>>(H, Hb, Htb, hpart,
                                                   Wmap, Wb, Q1w, Q1wb, Q2w, Q2wb, Q12w, Q12wb);
        reduce_hsum<<<dim3(16), blk, 0, stream>>>(hpart, Hsum);

        // 1. Q1b = bf16(Q1wb @ Wb^T + bmap)                 [118,512]
        gemm_mfma_p<5><<<dim3(2), dim3(512), 0, stream>>>(
            Q1wb, 320, 0, Wb, 320, 0, Q1b, 512, 0, 118, 512, 2, 1, 10,
            bmap, nullptr, 0, nullptr, 0, nullptr, nullptr, nullptr, nullptr);
        // 2. Embb = bf16(Q2wb @ Wb^T + bmap)                [8929,512]
        gemm_mfma_p<5><<<dim3(140), dim3(512), 0, stream>>>(
            Q2wb, 320, 0, Wb, 320, 0, Embb, 512, 0, 8929, 512, 2, 70, 10,
            bmap, nullptr, 0, nullptr, 0, nullptr, nullptr, nullptr, nullptr);
        // 3. E1x[b] = bf16(expm1(Q1b @ Htb^T)), level-1 row partials  (q-kernel)
        gemm_mfma_q<<<dim3(128), dim3(256), 0, stream>>>(
            Q1b, 512, 0, Htb, 512, 2048*512, E1x, 2048, 128*2048,
            118, 16, 1, 16, part1, 944);
        // 4. invs1 = 1/(2000 + sum part1)
        invs_k<<<dim3(4), blk, 0, stream>>>(part1, 944, invs1, 944, 16);
        // 5. C1tb[b] = bf16( ((E1x @ Hb^T + Hsum)*invs1)^T )   [8,512,128]
        gemm_mfma_p<40><<<dim3(16), dim3(512), 0, stream>>>(
            E1x, 2048, 128*2048, Hb, 2048, 512*2048, C1tb, 128, 512*128, 118, 512, 2, 1, 64,
            nullptr, nullptr, 0, nullptr, 0, Hsum, invs1, nullptr, nullptr);
        // 6. Q2b[b] = bf16((Q12wb @ C1tb^T) * Embb)         [8,8929,512]
        gemm_mfma_p<132><<<dim3(1120), dim3(512), 0, stream>>>(
            Q12wb, 128, 0, C1tb, 128, 512*128, Q2b, 512, N2*D, 8929, 512, 2, 70, 4,
            nullptr, (const float*)Embb, 512, nullptr, 0, nullptr, nullptr, nullptr, nullptr);
        // 7. A2b = bf16(expm1(Q2b @ Htb^T)), level-2 row partials  (q-kernel)
        gemm_mfma_q<<<dim3(4480), dim3(256), 0, stream>>>(
            Q2b, 512, N2*D, Htb, 512, 2048*512, A2b, 2048, N2*2048,
            8929, 16, 35, 16, part, 8ll*8929);
        // 8. invs = 1/(2000 + sum partials)
        invs_k<<<dim3(280), blk, 0, stream>>>(part, 8ll*8929, invs, (int)(B*N2), 16);
        // 9. C2[b] = (A2b @ Hb^T + Hsum) * invs  +  fused A2 write (nx==0)
        gemm_mfma_p<96><<<dim3(1120), dim3(512), 0, stream>>>(
            A2b, 2048, N2*2048, Hb, 2048, 512*2048, C2, 512, N2*D, 8929, 512, 2, 70, 64,
            nullptr, nullptr, 0, nullptr, 0, Hsum, invs, A2, part);
        return;
    }

    // ---------------- fallback paths ----------------
    float* Q1  = A2;
    float* emb = Q1  + N1*D;
    float* E1  = emb + N2*D;
    float* C1  = E1  + B*N1*L;

    gemm_f32<64,64,4,4,true,true,true,false><<<dim3(8,2,1), blk, 0, stream>>>(
        Q1w, 300, 0, Wmap, 300, 0, Q1, 512, 0, (int)N1, (int)D, 300, bmap, nullptr, 0);
    gemm_f32<64,64,4,4,true,true,true,false><<<dim3(8,140,1), blk, 0, stream>>>(
        Q2w, 300, 0, Wmap, 300, 0, emb, 512, 0, (int)N2, (int)D, 300, bmap, nullptr, 0);
    gemm_f32<64,64,4,4,false,true,true,false><<<dim3(32,2,8), blk, 0, stream>>>(
        Q1, 512, 0, H, 2000, D*L, E1, 2000, N1*L, (int)N1, (int)L, (int)D, nullptr, nullptr, 0);
    softmax_rows<<<dim3((unsigned)(B*N1)), blk, 0, stream>>>(E1, (int)L, nullptr, 0);
    gemm_f32<64,64,4,4,true,true,true,false><<<dim3(8,2,8), blk, 0, stream>>>(
        E1, 2000, N1*L, H, 2000, D*L, C1, 512, N1*D, (int)N1, (int)D, (int)L, nullptr, nullptr, 0);

    constexpr long long HBE = 8ll*512*2048;
    if (ws_size >= (size_t)(2*HBE*sizeof(unsigned short))) {
        unsigned short* Hb  = (unsigned short*)d_ws;
        unsigned short* Htb = Hb + HBE;
        cvt_pad_bf16<<<dim3(4096), blk, 0, stream>>>(H, Hb);
        cvt_transpose_bf16<<<dim3(32,8,8), blk, 0, stream>>>(H, Htb);
        unsigned short* Q2b = (unsigned short*)C2;
        gemm_f32<64,64,4,4,false,false,true,true><<<dim3(8,140,8), blk, 0, stream>>>(
            Q12w, 118, 0, C1, 512, N1*D, Q2b, 512, N2*D, (int)N2, (int)D, (int)N1, nullptr, emb, 512);
        gemm_mfma_p<0><<<dim3(4480), dim3(512), 0, stream>>>(
            Q2b, 512, N2*D, Htb, 512, 2048*512, A2, 2000, N2*L, (int)N2, (int)L, 8, 70, 16,
            nullptr, nullptr, 0, nullptr, 0, nullptr, nullptr, nullptr, nullptr);
        softmax_rows<<<dim3((unsigned)(B*N2)), blk, 0, stream>>>(A2, (int)L, nullptr, 0);
        gemm_mfma<true><<<dim3(2,70,8), dim3(512), 0, stream>>>(
            A2, 2000, N2*L, Hb, 2048, 512*2048, C2, 512, N2*D,
            (int)N2, (int)D, 2000, 63);
    } else {
        float* Q2 = C2;
        gemm_f32<64,64,4,4,false,false,true,false><<<dim3(8,140,8), blk, 0, stream>>>(
            Q12w, 118, 0, C1, 512, N1*D, Q2, 512, N2*D, (int)N2, (int)D, (int)N1, nullptr, emb, 512);
        gemm_f32<128,128,8,8,false,true,true,false><<<dim3(16,70,8), blk, 0, stream>>>(
            Q2, 512, N2*D, H, 2000, D*L, A2, 2000, N2*L, (int)N2, (int)L, (int)D, nullptr, nullptr, 0);
        softmax_rows<<<dim3((unsigned)(B*N2)), blk, 0, stream>>>(A2, (int)L, nullptr, 0);
        gemm_f32<128,128,8,8,true,true,true,false><<<dim3(4,70,8), blk, 0, stream>>>(
            A2, 2000, N2*L, H, 2000, D*L, C2, 512, N2*D, (int)N2, (int)D, (int)L, nullptr, nullptr, 0);
    }
}

// Round 10
// 723.995 us; speedup vs baseline: 1.0520x; 1.0520x over previous
//
#include <hip/hip_runtime.h>

typedef short    bf16x8 __attribute__((ext_vector_type(8)));
typedef float    f32x4  __attribute__((ext_vector_type(4)));
typedef unsigned short u16x8 __attribute__((ext_vector_type(8)));

__device__ __forceinline__ unsigned short f2bf(float f) {
    unsigned u = __float_as_uint(f);
    return (unsigned short)((u + 0x7fffu + ((u >> 16) & 1u)) >> 16);
}
__device__ __forceinline__ float bf2f(unsigned short h) {
    return __uint_as_float((unsigned)h << 16);
}

template<bool> struct otype            { using T = float; };
template<>     struct otype<true>      { using T = unsigned short; };

// ---------------------------------------------------------------------------
// Generic tiled fp32 GEMM (fallback path only).
// ---------------------------------------------------------------------------
template<int BM,int BN,int TM,int TN,bool BT,bool VA,bool VB,bool OB>
__launch_bounds__(256)
__global__ void gemm_f32(const float* __restrict__ A, int lda, long long sA,
                         const float* __restrict__ B, int ldb, long long sB,
                         void* __restrict__ Cv, int ldc, long long sC,
                         int M, int N, int K,
                         const float* __restrict__ bias,
                         const float* __restrict__ mul, int mulld)
{
    constexpr int BK  = 16;
    constexpr int GSA = BM*4/TM;
    constexpr int GSB = BN*4/TN;
    __shared__ float As[BK][BM+4];
    __shared__ float Bs[BK][BN+4];

    const int bz = blockIdx.z;
    A += (long long)bz * sA;
    B += (long long)bz * sB;
    using OT = typename otype<OB>::T;
    OT* C = (OT*)Cv + (long long)bz * sC;
    const int m0 = blockIdx.y * BM;
    const int n0 = blockIdx.x * BN;
    const int tid = threadIdx.x;
    const int tm = tid >> 4;
    const int tn = tid & 15;

    float acc[TM][TN];
#pragma unroll
    for (int i=0;i<TM;++i)
#pragma unroll
        for (int j=0;j<TN;++j) acc[i][j]=0.f;

    for (int k0=0;k0<K;k0+=BK) {
        if constexpr (VA) {
#pragma unroll
            for (int r=0;r<BM*BK/1024;++r) {
                int v = tid + r*256;
                int m = v >> 2, k4 = (v & 3)*4;
                int gm = m0+m, gk = k0+k4;
                float4 val = make_float4(0.f,0.f,0.f,0.f);
                if (gm < M) {
                    if (gk+3 < K) {
                        val = *reinterpret_cast<const float4*>(A + (long long)gm*lda + gk);
                    } else {
                        float t0 = (gk   < K) ? A[(long long)gm*lda+gk  ] : 0.f;
                        float t1 = (gk+1 < K) ? A[(long long)gm*lda+gk+1] : 0.f;
                        float t2 = (gk+2 < K) ? A[(long long)gm*lda+gk+2] : 0.f;
                        val = make_float4(t0,t1,t2,0.f);
                    }
                }
                As[k4+0][m]=val.x; As[k4+1][m]=val.y; As[k4+2][m]=val.z; As[k4+3][m]=val.w;
            }
        } else {
#pragma unroll
            for (int r=0;r<BM*BK/256;++r) {
                int e = tid + r*256;
                int m = e >> 4, k = e & 15;
                int gm=m0+m, gk=k0+k;
                As[k][m] = (gm<M && gk<K) ? A[(long long)gm*lda+gk] : 0.f;
            }
        }
        if constexpr (!BT) {
            if constexpr (VB) {
#pragma unroll
                for (int r=0;r<BK*BN/1024;++r) {
                    int v = tid + r*256;
                    int k = v / (BN/4), n4 = (v % (BN/4))*4;
                    int gk=k0+k, gn=n0+n4;
                    float4 val = make_float4(0.f,0.f,0.f,0.f);
                    if (gk < K) {
                        if (gn+3 < N) {
                            val = *reinterpret_cast<const float4*>(B + (long long)gk*ldb + gn);
                        } else {
                            float t0=(gn  <N)?B[(long long)gk*ldb+gn  ]:0.f;
                            float t1=(gn+1<N)?B[(long long)gk*ldb+gn+1]:0.f;
                            float t2=(gn+2<N)?B[(long long)gk*ldb+gn+2]:0.f;
                            val = make_float4(t0,t1,t2,0.f);
                        }
                    }
                    Bs[k][n4+0]=val.x; Bs[k][n4+1]=val.y; Bs[k][n4+2]=val.z; Bs[k][n4+3]=val.w;
                }
            } else {
#pragma unroll
                for (int r=0;r<BK*BN/256;++r) {
                    int e = tid + r*256;
                    int k = e / BN, n = e % BN;
                    int gk=k0+k, gn=n0+n;
                    Bs[k][n] = (gk<K && gn<N) ? B[(long long)gk*ldb+gn] : 0.f;
                }
            }
        } else {
            if constexpr (VB) {
#pragma unroll
                for (int r=0;r<BN*BK/1024;++r) {
                    int v = tid + r*256;
                    int n = v >> 2, k4 = (v&3)*4;
                    int gn=n0+n, gk=k0+k4;
                    float4 val = make_float4(0.f,0.f,0.f,0.f);
                    if (gn < N) {
                        if (gk+3 < K) {
                            val = *reinterpret_cast<const float4*>(B + (long long)gn*ldb + gk);
                        } else {
                            float t0=(gk  <K)?B[(long long)gn*ldb+gk  ]:0.f;
                            float t1=(gk+1<K)?B[(long long)gn*ldb+gk+1]:0.f;
                            float t2=(gk+2<K)?B[(long long)gn*ldb+gk+2]:0.f;
                            val=make_float4(t0,t1,t2,0.f);
                        }
                    }
                    Bs[k4+0][n]=val.x; Bs[k4+1][n]=val.y; Bs[k4+2][n]=val.z; Bs[k4+3][n]=val.w;
                }
            } else {
#pragma unroll
                for (int r=0;r<BN*BK/256;++r) {
                    int e = tid + r*256;
                    int n = e >> 4, k = e & 15;
                    int gn=n0+n, gk=k0+k;
                    Bs[k][n] = (gn<N && gk<K) ? B[(long long)gn*ldb+gk] : 0.f;
                }
            }
        }
        __syncthreads();
#pragma unroll
        for (int kk=0;kk<BK;++kk) {
            float a[TM], bb[TN];
#pragma unroll
            for (int g=0;g<TM/4;++g) {
                float4 t = *reinterpret_cast<const float4*>(&As[kk][g*GSA + tm*4]);
                a[4*g+0]=t.x; a[4*g+1]=t.y; a[4*g+2]=t.z; a[4*g+3]=t.w;
            }
#pragma unroll
            for (int g=0;g<TN/4;++g) {
                float4 t = *reinterpret_cast<const float4*>(&Bs[kk][g*GSB + tn*4]);
                bb[4*g+0]=t.x; bb[4*g+1]=t.y; bb[4*g+2]=t.z; bb[4*g+3]=t.w;
            }
#pragma unroll
            for (int i=0;i<TM;++i)
#pragma unroll
                for (int j=0;j<TN;++j)
                    acc[i][j] = fmaf(a[i], bb[j], acc[i][j]);
        }
        __syncthreads();
    }
#pragma unroll
    for (int i=0;i<TM;++i) {
        int row = m0 + (i>>2)*GSA + tm*4 + (i&3);
        if (row < M) {
#pragma unroll
            for (int j=0;j<TN;++j) {
                int col = n0 + (j>>2)*GSB + tn*4 + (j&3);
                if (col < N) {
                    float val = acc[i][j];
                    if (bias) val += bias[col];
                    if (mul)  val *= mul[(long long)row*mulld + col];
                    if constexpr (OB) C[(long long)row*ldc + col] = f2bf(val);
                    else              C[(long long)row*ldc + col] = val;
                }
            }
        }
    }
}

// ---------------------------------------------------------------------------
// Pipelined bf16 MFMA GEMM, B^T form: base = sum_k A[m,k]*Bt[n,k].
// BM=128, BN=256, BK=32, 512 thr = 8 waves (2x4), wave tile 64x64.
// Ring of 3 LDS buffers, counted vmcnt; T2 swizzle; XCD-bijective remap.
// Epilogue flags F: 1=BIAS 2=MUL(f32) 128=MULB(bf16) 4=OB(bf16, LDS-staged
//   coalesced store) 8=OT(bf16 transposed; +32 applies AFF first)
//   16=EXPM1 (x=exp(acc)-1 -> bf16 LDS-staged coalesced store + per-row
//             partial sums of stored-bf16 x -> partial[])
//   32=AFF   (val=(acc+hsum[bz*Ncols+col])*invs[bz*M+row], fp32 out)
//   64=A2W   (nx==0 blocks ALSO write a2out[row][k]=(1+x)*invs[row] fp32
//             from the staged A-tile in the K-loop; invalid lanes -> dump)
// ---------------------------------------------------------------------------
template<unsigned F>
__launch_bounds__(512, 4)
__global__ void gemm_mfma_p(const unsigned short* __restrict__ A, int lda, long long sA,
                            const unsigned short* __restrict__ Bt, int ldb, long long sB,
                            void* __restrict__ Cv, int ldc, long long sC,
                            int M, int Ncols, int NX, int NY, int NT,
                            const float* __restrict__ bias,
                            const float* __restrict__ mul, int ldm,
                            float* __restrict__ partial, long long pstride,
                            const float* __restrict__ hsum,
                            const float* __restrict__ invs,
                            float* __restrict__ a2out,
                            float* __restrict__ dump)
{
    __shared__ unsigned short lds[3][12288];    // 72KB ring; reused as 64KB epilogue tile

    // bijective XCD-chunked remap (m204 formula)
    const int nwg = gridDim.x;
    const int q = nwg >> 3, r = nwg & 7;
    const int xcd = blockIdx.x & 7, idx = blockIdx.x >> 3;
    const int wg = (xcd < r ? xcd*(q+1) : r*(q+1) + (xcd-r)*q) + idx;
    const int nx = wg % NX;
    const int t1 = wg / NX;
    const int my = t1 % NY;
    const int bz = t1 / NY;

    const int tid  = threadIdx.x;
    const int lane = tid & 63, wid = tid >> 6;
    const int wr = wid >> 2, wc = wid & 3;
    const int fr = lane & 15, fq = lane >> 4;
    const int m0 = my * 128;
    const int n0 = nx * 256;

    A  += (long long)bz * sA;
    Bt += (long long)bz * sB;

    const int srow = tid >> 2;
    const int scz  = (tid & 3) ^ ((srow >> 1) & 3);
    long long arow = m0 + srow; if (arow > M-1) arow = M-1;
    const unsigned short* aSrc  = A  + arow*lda + scz*8;
    const unsigned short* bSrc0 = Bt + (long long)(n0 + srow)*ldb + scz*8;
    const unsigned short* bSrc1 = bSrc0 + 128ll*ldb;

    // A2W setup (before pipeline so the invs load drains here, not in-loop)
    bool wrblk = false, a2ok = false;
    float invv = 0.f;
    float* a2p = nullptr;
    if constexpr ((F & 64) != 0) {
        wrblk = (nx == 0);
        if (wrblk) {
            const int rrow = m0 + srow;
            a2ok = rrow < M;
            const long long ridx = (long long)bz*M + (a2ok ? rrow : M-1);
            invv = invs[ridx];
            asm volatile("" : "+v"(invv));   // materialize: load-wait lands HERE
            a2p = a2out + ridx*2000ll;
        }
    }

    int aoff[4], boff[4];
#pragma unroll
    for (int m=0;m<4;++m) {
        const int ra = wr*64 + m*16 + fr;
        aoff[m] = ra*64 + ((fq ^ ((ra>>1)&3))*16);
    }
#pragma unroll
    for (int n=0;n<4;++n) {
        const int rb = wc*64 + n*16 + fr;
        boff[n] = 8192 + rb*64 + ((fq ^ ((rb>>1)&3))*16);
    }

    f32x4 acc[4][4];
#pragma unroll
    for (int i=0;i<4;++i)
#pragma unroll
        for (int j=0;j<4;++j) acc[i][j] = (f32x4)(0.f);

    auto stage = [&](int s, int t) {
        const int koff = t*32;
        char* base = (char*)&lds[s][0];
        __builtin_amdgcn_global_load_lds(
            (const __attribute__((address_space(1))) void*)(aSrc + koff),
            (__attribute__((address_space(3))) void*)(base + tid*16), 16, 0, 0);
        __builtin_amdgcn_global_load_lds(
            (const __attribute__((address_space(1))) void*)(bSrc0 + koff),
            (__attribute__((address_space(3))) void*)(base + 8192 + tid*16), 16, 0, 0);
        __builtin_amdgcn_global_load_lds(
            (const __attribute__((address_space(1))) void*)(bSrc1 + koff),
            (__attribute__((address_space(3))) void*)(base + 16384 + tid*16), 16, 0, 0);
    };

    stage(0, 0);
    stage(1, NT > 1 ? 1 : 0);
    asm volatile("s_waitcnt vmcnt(3)" ::: "memory");
    __builtin_amdgcn_s_barrier();

    int cur = 0, stg = 2;
    for (int kt = 0; kt < NT; ++kt) {
        int tnx = kt + 2; if (tnx > NT-1) tnx = NT-1;   // uniform issue count
        stage(stg, tnx);
        const char* bp = (const char*)&lds[cur][0];
        bf16x8 a[4], b[4];
#pragma unroll
        for (int m=0;m<4;++m) a[m] = *(const bf16x8*)(bp + aoff[m]);
#pragma unroll
        for (int n=0;n<4;++n) b[n] = *(const bf16x8*)(bp + boff[n]);
        __builtin_amdgcn_s_setprio(1);
#pragma unroll
        for (int m=0;m<4;++m)
#pragma unroll
            for (int n=0;n<4;++n)
                acc[m][n] = __builtin_amdgcn_mfma_f32_16x16x32_bf16(a[m], b[n], acc[m][n], 0, 0, 0);
        __builtin_amdgcn_s_setprio(0);
        if constexpr ((F & 64) != 0) {
            if (wrblk) {
                u16x8 av = *(const u16x8*)(bp + (tid << 4));
                const int col0 = kt*32 + scz*8;
                const bool ok = a2ok && (col0 < 2000);
                float* p0 = ok ? (a2p + col0) : (dump + (tid << 3));
                float4 o0, o1;
                o0.x = fmaf(bf2f((unsigned short)av[0]), invv, invv);
                o0.y = fmaf(bf2f((unsigned short)av[1]), invv, invv);
                o0.z = fmaf(bf2f((unsigned short)av[2]), invv, invv);
                o0.w = fmaf(bf2f((unsigned short)av[3]), invv, invv);
                o1.x = fmaf(bf2f((unsigned short)av[4]), invv, invv);
                o1.y = fmaf(bf2f((unsigned short)av[5]), invv, invv);
                o1.z = fmaf(bf2f((unsigned short)av[6]), invv, invv);
                o1.w = fmaf(bf2f((unsigned short)av[7]), invv, invv);
                *(float4*)(p0    ) = o0;
                *(float4*)(p0 + 4) = o1;
            }
        }
        asm volatile("s_waitcnt lgkmcnt(0)" ::: "memory");
        if constexpr ((F & 64) != 0) {
            if (wrblk) asm volatile("s_waitcnt vmcnt(5)" ::: "memory");
            else       asm volatile("s_waitcnt vmcnt(3)" ::: "memory");
        } else {
            asm volatile("s_waitcnt vmcnt(3)" ::: "memory");
        }
        __builtin_amdgcn_s_barrier();
        cur = (cur == 2) ? 0 : cur + 1;
        stg = (stg == 2) ? 0 : stg + 1;
    }

    // ---- epilogues (C/D layout: col = lane&15, row = (lane>>4)*4 + j) ----
    if constexpr ((F & 16) != 0) {
        asm volatile("s_waitcnt vmcnt(0)" ::: "memory");
        __builtin_amdgcn_s_barrier();
        unsigned short* ep = (unsigned short*)&lds[0][0];
        unsigned short* Cb = (unsigned short*)Cv + (long long)bz * sC;
#pragma unroll
        for (int m=0;m<4;++m) {
            const int rl = wr*64 + m*16 + fq*4;
#pragma unroll
            for (int n=0;n<4;++n) {
                const int cl = wc*64 + n*16 + fr;
                const int cb = cl*2;
#pragma unroll
                for (int j=0;j<4;++j) {
                    const int row = rl + j;
                    float x = __expf(acc[m][n][j]) - 1.0f;
                    const int ch = (cb>>5) ^ ((row>>2)&3);
                    *(unsigned short*)((char*)ep + row*512 + (ch<<5) + (cb&31)) = f2bf(x);
                }
            }
        }
        __syncthreads();
        const int rq = tid >> 3;
        const int cq = tid & 7;
#pragma unroll
        for (int half=0; half<2; ++half) {
            const int row = rq + half*64;
            const int grow = m0 + row;
            float s = 0.f;
#pragma unroll
            for (int win=0; win<4; ++win) {
                const int cb = cq*16 + win*128;
                const int ch = (cb>>5) ^ ((row>>2)&3);
                u16x8 v = *(const u16x8*)((const char*)ep + row*512 + (ch<<5) + (cb&31));
#pragma unroll
                for (int i=0;i<8;++i) s += bf2f((unsigned short)v[i]);
                if (grow < M) *(u16x8*)(Cb + (long long)grow*ldc + n0 + (cb>>1)) = v;
            }
            s += __shfl_xor(s, 1); s += __shfl_xor(s, 2); s += __shfl_xor(s, 4);
            if (cq == 0 && grow < M)
                partial[(long long)nx*pstride + (long long)bz*M + grow] = s;
        }
    } else if constexpr ((F & 8) != 0) {
        unsigned short* Ct = (unsigned short*)Cv + (long long)bz * sC;
#pragma unroll
        for (int m=0;m<4;++m) {
            const int rb = m0 + wr*64 + m*16 + fq*4;
#pragma unroll
            for (int n=0;n<4;++n) {
                const int col = n0 + wc*64 + n*16 + fr;
                if (col < Ncols) {
                    float hv = 0.f;
                    if constexpr ((F & 32) != 0) hv = hsum[(long long)bz*Ncols + col];
#pragma unroll
                    for (int j=0;j<4;++j) {
                        const int row = rb + j;
                        float val = 0.f;
                        if (row < M) {
                            val = acc[m][n][j];
                            if constexpr ((F & 32) != 0) val = (val + hv) * invs[(long long)bz*M + row];
                        }
                        Ct[(long long)col*ldc + row] = f2bf(val);
                    }
                }
            }
        }
    } else if constexpr ((F & 4) != 0) {
        asm volatile("s_waitcnt vmcnt(0)" ::: "memory");
        __builtin_amdgcn_s_barrier();
        unsigned short* ep = (unsigned short*)&lds[0][0];
        unsigned short* Cb = (unsigned short*)Cv + (long long)bz * sC;
#pragma unroll
        for (int m=0;m<4;++m) {
            const int rl = wr*64 + m*16 + fq*4;
#pragma unroll
            for (int n=0;n<4;++n) {
                const int cl = wc*64 + n*16 + fr;
                const int gcol = n0 + cl;
                const int cb = cl*2;
                float bv = 0.f;
                if constexpr ((F & 1) != 0) bv = bias[gcol];
#pragma unroll
                for (int j=0;j<4;++j) {
                    const int row = rl + j;
                    float val = acc[m][n][j];
                    if constexpr ((F & 1) != 0) val += bv;
                    if constexpr ((F & 128) != 0) {
                        int mr = m0 + row; if (mr > M-1) mr = M-1;
                        val *= bf2f(((const unsigned short*)mul)[(long long)mr*ldm + gcol]);
                    }
                    if constexpr ((F & 2) != 0) {
                        int mr = m0 + row; if (mr > M-1) mr = M-1;
                        val *= mul[(long long)mr*ldm + gcol];
                    }
                    const int ch = (cb>>5) ^ ((row>>2)&3);
                    *(unsigned short*)((char*)ep + row*512 + (ch<<5) + (cb&31)) = f2bf(val);
                }
            }
        }
        __syncthreads();
        const int rq = tid >> 3;
        const int cq = tid & 7;
#pragma unroll
        for (int half=0; half<2; ++half) {
            const int row = rq + half*64;
            const int grow = m0 + row;
#pragma unroll
            for (int win=0; win<4; ++win) {
                const int cb = cq*16 + win*128;
                const int ch = (cb>>5) ^ ((row>>2)&3);
                u16x8 v = *(const u16x8*)((const char*)ep + row*512 + (ch<<5) + (cb&31));
                const int gc = n0 + (cb>>1);
                if (grow < M && gc < Ncols) *(u16x8*)(Cb + (long long)grow*ldc + gc) = v;
            }
        }
    } else {
        float* Cf = (float*)Cv + (long long)bz * sC;
#pragma unroll
        for (int m=0;m<4;++m) {
            const int rb = m0 + wr*64 + m*16 + fq*4;
#pragma unroll
            for (int n=0;n<4;++n) {
                const int col = n0 + wc*64 + n*16 + fr;
                if (col < Ncols) {
                    float bv = 0.f, hv = 0.f;
                    if constexpr ((F & 1) != 0) bv = bias[col];
                    if constexpr ((F & 32) != 0) hv = hsum[(long long)bz*Ncols + col];
#pragma unroll
                    for (int j=0;j<4;++j) {
                        const int row = rb + j;
                        if (row < M) {
                            float val = acc[m][n][j];
                            if constexpr ((F & 1)   != 0) val += bv;
                            if constexpr ((F & 2)   != 0) val *= mul[(long long)row*ldm + col];
                            if constexpr ((F & 128) != 0) val *= bf2f(((const unsigned short*)mul)[(long long)row*ldm + col]);
                            if constexpr ((F & 32)  != 0) val = (val + hv) * invs[(long long)bz*M + row];
                            Cf[(long long)row*ldc + col] = val;
                        }
                    }
                }
            }
        }
    }
}

// ---------------------------------------------------------------------------
// 2-phase MFMA GEMM (tier-2 fallback C2, fp32 A on the fly).
// ---------------------------------------------------------------------------
template<bool AF32>
__launch_bounds__(512, 2)
__global__ void gemm_mfma(const void* __restrict__ Ain, int lda, long long sA,
                          const unsigned short* __restrict__ Bt, int ldb, long long sB,
                          float* __restrict__ C, int ldc, long long sC,
                          int M, int N, int K, int NT)
{
    __shared__ unsigned short As[2][128*32];
    __shared__ unsigned short Bs[2][256*32];

    const int tid  = threadIdx.x;
    const int lane = tid & 63, wid = tid >> 6;
    const int wr = wid >> 2, wc = wid & 3;
    const int fr = lane & 15, fq = lane >> 4;
    const int bz = blockIdx.z;
    const int m0 = blockIdx.y * 128;
    const int n0 = blockIdx.x * 256;

    const unsigned short* Ab = nullptr;
    const float*          Af = nullptr;
    if constexpr (AF32) Af = (const float*)Ain + (long long)bz * sA;
    else                Ab = (const unsigned short*)Ain + (long long)bz * sA;
    Bt += (long long)bz * sB;
    C  += (long long)bz * sC;

    const int srow = tid >> 2;
    const int sc   = tid & 3;
    const int scz  = sc ^ ((srow >> 1) & 3);
    int arow = m0 + srow; if (arow > M-1) arow = M-1;
    const bool am_ok = (m0 + srow) < M;
    const long long brow0 = n0 + srow;
    const long long brow1 = n0 + 128 + srow;
    const int ldsA  = wid << 10;
    const int ldsB0 = wid << 10;
    const int ldsB1 = 8192 + (wid << 10);

    f32x4 acc[4][4];
#pragma unroll
    for (int i=0;i<4;++i)
#pragma unroll
        for (int j=0;j<4;++j) acc[i][j] = (f32x4)(0.f);

    auto stage = [&](int buf, int t) {
        const long long koff = (long long)t * 32;
        __builtin_amdgcn_global_load_lds(
            (const __attribute__((address_space(1))) void*)(Bt + brow0*ldb + koff + scz*8),
            (__attribute__((address_space(3))) void*)((char*)&Bs[buf][0] + ldsB0), 16, 0, 0);
        __builtin_amdgcn_global_load_lds(
            (const __attribute__((address_space(1))) void*)(Bt + brow1*ldb + koff + scz*8),
            (__attribute__((address_space(3))) void*)((char*)&Bs[buf][0] + ldsB1), 16, 0, 0);
        if constexpr (!AF32) {
            __builtin_amdgcn_global_load_lds(
                (const __attribute__((address_space(1))) void*)(Ab + (long long)arow*lda + koff + scz*8),
                (__attribute__((address_space(3))) void*)((char*)&As[buf][0] + ldsA), 16, 0, 0);
        } else {
            const float* src = Af + (long long)arow*lda + koff + scz*8;
            const int kk = t*32 + scz*8;
            float4 z = make_float4(0.f,0.f,0.f,0.f);
            float4 v0 = (am_ok && kk   < K) ? *(const float4*)(src  ) : z;
            float4 v1 = (am_ok && kk+4 < K) ? *(const float4*)(src+4) : z;
            u16x8 o;
            o[0]=f2bf(v0.x); o[1]=f2bf(v0.y); o[2]=f2bf(v0.z); o[3]=f2bf(v0.w);
            o[4]=f2bf(v1.x); o[5]=f2bf(v1.y); o[6]=f2bf(v1.z); o[7]=f2bf(v1.w);
            *(u16x8*)((char*)&As[buf][0] + tid*16) = o;
        }
    };

    stage(0, 0);
    int cur = 0;
    for (int t = 0; t < NT; ++t) {
        __syncthreads();
        if (t + 1 < NT) stage(cur ^ 1, t + 1);
        const unsigned short* as = As[cur];
        const unsigned short* bs = Bs[cur];
        bf16x8 a[4], b[4];
#pragma unroll
        for (int m=0;m<4;++m) {
            const int ra = wr*64 + m*16 + fr;
            a[m] = *(const bf16x8*)(as + ra*32 + (fq ^ ((ra>>1)&3))*8);
        }
#pragma unroll
        for (int n=0;n<4;++n) {
            const int rb = wc*64 + n*16 + fr;
            b[n] = *(const bf16x8*)(bs + rb*32 + (fq ^ ((rb>>1)&3))*8);
        }
        __builtin_amdgcn_s_setprio(1);
#pragma unroll
        for (int m=0;m<4;++m)
#pragma unroll
            for (int n=0;n<4;++n)
                acc[m][n] = __builtin_amdgcn_mfma_f32_16x16x32_bf16(a[m], b[n], acc[m][n], 0, 0, 0);
        __builtin_amdgcn_s_setprio(0);
        cur ^= 1;
    }
#pragma unroll
    for (int m=0;m<4;++m) {
        const int rb = m0 + wr*64 + m*16 + fq*4;
#pragma unroll
        for (int n=0;n<4;++n) {
            const int col = n0 + wc*64 + n*16 + fr;
            if (col < N) {
#pragma unroll
                for (int j=0;j<4;++j) {
                    const int row = rb + j;
                    if (row < M) C[(long long)row*ldc + col] = acc[m][n][j];
                }
            }
        }
    }
}

// ---------------------------------------------------------------------------
// mega_prep: ONE launch doing all input prep.
// ---------------------------------------------------------------------------
__global__ __launch_bounds__(256) void mega_prep(const float* __restrict__ H,
                                                 unsigned short* __restrict__ Hb,
                                                 unsigned short* __restrict__ Htb,
                                                 float* __restrict__ hpart,
                                                 const float* __restrict__ Wmap,  unsigned short* __restrict__ Wb,
                                                 const float* __restrict__ Q1w,   unsigned short* __restrict__ Q1wb,
                                                 const float* __restrict__ Q2w,   unsigned short* __restrict__ Q2wb,
                                                 const float* __restrict__ Q12w,  unsigned short* __restrict__ Q12wb)
{
    __shared__ unsigned short T[64][80];
    const int tid = threadIdx.x;
    int id = blockIdx.x;
    if (id < 2048) {
        const int lt = id & 31;
        const int dt = (id >> 5) & 7;
        const int bz = id >> 8;
        const int d0 = dt * 64;
        const int l0 = lt * 64;
        const float* Hsrc = H + ((long long)bz*512 + d0) * 2000;
        const int dl = tid >> 2;
        const int lc = (tid & 3) * 16;
        float4 v[4];
        float s = 0.f;
#pragma unroll
        for (int i=0;i<4;++i) {
            const int gl = l0 + lc + i*4;
            v[i] = make_float4(0.f,0.f,0.f,0.f);
            if (gl < 2000) v[i] = *(const float4*)(Hsrc + (long long)dl*2000 + gl);
            s += (v[i].x + v[i].y) + (v[i].z + v[i].w);
            T[lc+i*4+0][dl] = f2bf(v[i].x);
            T[lc+i*4+1][dl] = f2bf(v[i].y);
            T[lc+i*4+2][dl] = f2bf(v[i].z);
            T[lc+i*4+3][dl] = f2bf(v[i].w);
        }
        {
            unsigned short* hb = Hb + ((long long)bz*512 + d0 + dl)*2048 + l0 + lc;
            u16x8 h0, h1;
            h0[0]=f2bf(v[0].x); h0[1]=f2bf(v[0].y); h0[2]=f2bf(v[0].z); h0[3]=f2bf(v[0].w);
            h0[4]=f2bf(v[1].x); h0[5]=f2bf(v[1].y); h0[6]=f2bf(v[1].z); h0[7]=f2bf(v[1].w);
            h1[0]=f2bf(v[2].x); h1[1]=f2bf(v[2].y); h1[2]=f2bf(v[2].z); h1[3]=f2bf(v[2].w);
            h1[4]=f2bf(v[3].x); h1[5]=f2bf(v[3].y); h1[6]=f2bf(v[3].z); h1[7]=f2bf(v[3].w);
            *(u16x8*)(hb    ) = h0;
            *(u16x8*)(hb + 8) = h1;
        }
        s += __shfl_xor(s, 1);
        s += __shfl_xor(s, 2);
        if ((tid & 3) == 0)
            hpart[(long long)lt*4096 + bz*512 + d0 + dl] = s;
        __syncthreads();
        unsigned short* Hdst = Htb + ((long long)bz*2048 + l0) * 512 + d0;
        const int ll = tid >> 2;
        const int dc = (tid & 3) * 16;
        u16x8 w0 = *(const u16x8*)&T[ll][dc];
        u16x8 w1 = *(const u16x8*)&T[ll][dc+8];
        *(u16x8*)(Hdst + (long long)ll*512 + dc    ) = w0;
        *(u16x8*)(Hdst + (long long)ll*512 + dc + 8) = w1;
        return;
    }
    id -= 2048;
    if (id < 640) {
        const int i = id*256 + tid;
        if (i < 512*320) {
            const int r2 = i/320, c = i - r2*320;
            Wb[i] = (c < 300) ? f2bf(Wmap[r2*300 + c]) : (unsigned short)0;
        }
    } else if (id < 788) {
        const int i = (id-640)*256 + tid;
        if (i < 118*320) {
            const int r2 = i/320, c = i - r2*320;
            Q1wb[i] = (c < 300) ? f2bf(Q1w[r2*300 + c]) : (unsigned short)0;
        }
    } else if (id < 11950) {
        const int i = (id-788)*256 + tid;
        if (i < 8929*320) {
            const int r2 = i/320, c = i - r2*320;
            Q2wb[i] = (c < 300) ? f2bf(Q2w[r2*300 + c]) : (unsigned short)0;
        }
    } else {
        const int i = (id-11950)*256 + tid;
        if (i < 8929*128) {
            const int r2 = i >> 7, c = i & 127;
            Q12wb[i] = (c < 118) ? f2bf(Q12w[r2*118 + c]) : (unsigned short)0;
        }
    }
}

// Hsum[r] = sum_{i<32} hpart[i][r],  r < 4096
__global__ __launch_bounds__(256) void reduce_hsum(const float* __restrict__ hpart,
                                                   float* __restrict__ Hsum)
{
    const int r = blockIdx.x*256 + threadIdx.x;
    float s = 0.f;
#pragma unroll
    for (int i=0;i<32;++i) s += hpart[(long long)i*4096 + r];
    Hsum[r] = s;
}

// invs[r] = 1 / (2000 + sum_{i<cnt} partial[i][r]),  r < n
__global__ __launch_bounds__(256) void invs_k(const float* __restrict__ partial,
                                              long long pstride,
                                              float* __restrict__ invs, int n, int cnt)
{
    const int r = blockIdx.x*256 + threadIdx.x;
    if (r < n) {
        float s = 0.f;
        for (int i=0;i<cnt;++i) s += partial[i*pstride + r];
        invs[r] = 1.0f / (2000.0f + s);
    }
}

// ---------------------------------------------------------------------------
// fallback-only kernels
// ---------------------------------------------------------------------------
__global__ __launch_bounds__(256) void cvt_pad_bf16(const float* __restrict__ H,
                                                    unsigned short* __restrict__ Hb)
{
    const long long idx = (long long)blockIdx.x * 256 + threadIdx.x;
    const long long row = idx >> 8;
    const int l0 = (int)(idx & 255) * 8;
    u16x8 o = (u16x8)(unsigned short)0;
    if (l0 + 8 <= 2000) {
        const float* s = H + row*2000 + l0;
        float4 v0 = *(const float4*)(s);
        float4 v1 = *(const float4*)(s+4);
        o[0]=f2bf(v0.x); o[1]=f2bf(v0.y); o[2]=f2bf(v0.z); o[3]=f2bf(v0.w);
        o[4]=f2bf(v1.x); o[5]=f2bf(v1.y); o[6]=f2bf(v1.z); o[7]=f2bf(v1.w);
    }
    *(u16x8*)(Hb + row*2048 + l0) = o;
}

__global__ __launch_bounds__(256) void cvt_transpose_bf16(const float* __restrict__ H,
                                                          unsigned short* __restrict__ Ht)
{
    __shared__ unsigned short T[64][80];
    const int bz = blockIdx.z;
    const int d0 = blockIdx.y * 64;
    const int l0 = blockIdx.x * 64;
    const float* Hsrc = H + ((long long)bz*512 + d0) * 2000;
    unsigned short* Hdst = Ht + ((long long)bz*2048 + l0) * 512 + d0;
    const int tid = threadIdx.x;
    const int dl = tid >> 2;
    const int lc = (tid & 3) * 16;
#pragma unroll
    for (int i=0;i<4;++i) {
        const int l = lc + i*4;
        const int gl = l0 + l;
        float4 v = make_float4(0.f,0.f,0.f,0.f);
        if (gl < 2000) v = *(const float4*)(Hsrc + (long long)dl*2000 + gl);
        T[l+0][dl] = f2bf(v.x);
        T[l+1][dl] = f2bf(v.y);
        T[l+2][dl] = f2bf(v.z);
        T[l+3][dl] = f2bf(v.w);
    }
    __syncthreads();
    const int ll = tid >> 2;
    const int dc = (tid & 3) * 16;
    u16x8 w0 = *(const u16x8*)&T[ll][dc];
    u16x8 w1 = *(const u16x8*)&T[ll][dc+8];
    *(u16x8*)(Hdst + (long long)ll*512 + dc    ) = w0;
    *(u16x8*)(Hdst + (long long)ll*512 + dc + 8) = w1;
}

__global__ __launch_bounds__(256) void softmax_rows(float* __restrict__ X, int L,
                                                    unsigned short* __restrict__ Xb, int Lb)
{
    const long long row = blockIdx.x;
    float* x = X + row * (long long)L;
    const int tid = threadIdx.x;
    const int nv = L >> 2;
    const bool h0 = tid < nv;
    const bool h1 = tid + 256 < nv;
    float4 t0 = make_float4(0.f,0.f,0.f,0.f);
    float4 t1 = make_float4(0.f,0.f,0.f,0.f);
    float mx = -3.402823e38f;
    if (h0) { t0 = *reinterpret_cast<const float4*>(x + 4*tid);
              mx = fmaxf(fmaxf(t0.x,t0.y), fmaxf(t0.z,t0.w)); }
    if (h1) { t1 = *reinterpret_cast<const float4*>(x + 4*(tid+256));
              mx = fmaxf(mx, fmaxf(fmaxf(t1.x,t1.y), fmaxf(t1.z,t1.w))); }
    __shared__ float sred[4];
#pragma unroll
    for (int o=32;o;o>>=1) mx = fmaxf(mx, __shfl_xor(mx, o));
    if ((tid & 63)==0) sred[tid>>6] = mx;
    __syncthreads();
    mx = fmaxf(fmaxf(sred[0],sred[1]), fmaxf(sred[2],sred[3]));
    __syncthreads();
    float s = 0.f;
    if (h0) {
        t0.x=__expf(t0.x-mx); t0.y=__expf(t0.y-mx); t0.z=__expf(t0.z-mx); t0.w=__expf(t0.w-mx);
        s += (t0.x+t0.y)+(t0.z+t0.w);
    }
    if (h1) {
        t1.x=__expf(t1.x-mx); t1.y=__expf(t1.y-mx); t1.z=__expf(t1.z-mx); t1.w=__expf(t1.w-mx);
        s += (t1.x+t1.y)+(t1.z+t1.w);
    }
#pragma unroll
    for (int o=32;o;o>>=1) s += __shfl_xor(s, o);
    if ((tid & 63)==0) sred[tid>>6] = s;
    __syncthreads();
    s = (sred[0]+sred[1])+(sred[2]+sred[3]);
    const float inv = 1.0f / s;
    if (h0) { t0.x*=inv; t0.y*=inv; t0.z*=inv; t0.w*=inv;
              *reinterpret_cast<float4*>(x + 4*tid) = t0; }
    if (h1) { t1.x*=inv; t1.y*=inv; t1.z*=inv; t1.w*=inv;
              *reinterpret_cast<float4*>(x + 4*(tid+256)) = t1; }
    if (Xb) {
        unsigned short* xb = Xb + row * (long long)Lb;
        if (h0) {
            ushort4 o; o.x=f2bf(t0.x); o.y=f2bf(t0.y); o.z=f2bf(t0.z); o.w=f2bf(t0.w);
            *reinterpret_cast<ushort4*>(xb + 4*tid) = o;
        }
        if (h1) {
            ushort4 o; o.x=f2bf(t1.x); o.y=f2bf(t1.y); o.z=f2bf(t1.z); o.w=f2bf(t1.w);
            *reinterpret_cast<ushort4*>(xb + 4*(tid+256)) = o;
        }
        if (tid < (Lb - L)/4) {
            ushort4 z; z.x=z.y=z.z=z.w=0;
            *reinterpret_cast<ushort4*>(xb + L + 4*tid) = z;
        }
    }
}

// ---------------------------------------------------------------------------
extern "C" void kernel_launch(void* const* d_in, const int* in_sizes, int n_in,
                              void* d_out, int out_size, void* d_ws, size_t ws_size,
                              hipStream_t stream)
{
    const float* H    = (const float*)d_in[0];  // [8,512,2000]
    const float* Q1w  = (const float*)d_in[1];  // [118,300]
    const float* Q2w  = (const float*)d_in[2];  // [8929,300]
    const float* Q12w = (const float*)d_in[3];  // [8929,118]
    const float* Wmap = (const float*)d_in[4];  // [512,300]
    const float* bmap = (const float*)d_in[5];  // [512]

    constexpr long long B=8, D=512, L=2000, N1=118, N2=8929;
    constexpr long long C2E = B*N2*D;
    float* out = (float*)d_out;
    float* C2  = out;            // [8,8929,512]
    float* A2  = out + C2E;      // [8,8929,2000]

    dim3 blk(256);

    // workspace layout (256B-aligned slots)
    size_t off = 0;
    auto alloc = [&](size_t n)->size_t { off = (off + 255) & ~(size_t)255; size_t o = off; off += n; return o; };
    const size_t oHb    = alloc(8ll*512*2048*2);
    const size_t oHtb   = alloc(8ll*2048*512*2);
    const size_t oWb    = alloc(512ll*320*2);
    const size_t oQWb   = alloc(9047ll*320*2);     // Q1wb rows 0..117 | Q2wb rows 118..9046
    const size_t oQ12wb = alloc(8929ll*128*2);
    const size_t oQEb   = alloc(9047ll*512*2);     // Q1b rows 0..117 | Embb rows 118..9046
    const size_t oE1x   = alloc(8ll*128*2048*2);
    const size_t oC1tb  = alloc(8ll*512*128*2);
    const size_t oQ2b   = alloc(8ll*8929*512*2);
    const size_t oA2b   = alloc(8ll*8929*2048*2);
    const size_t oPart  = alloc(8ll*8*8929*4);
    const size_t oPart1 = alloc(8ll*944*4);
    const size_t oInvs  = alloc(8ll*8929*4);
    const size_t oInvs1 = alloc(944ll*4);
    const size_t oHsum  = alloc(8ll*512*4);
    const size_t oHpart = alloc(32ll*4096*4);
    const size_t FULL_NEED = off;

    char* ws = (char*)d_ws;

    if (ws_size >= FULL_NEED) {
        unsigned short* Hb    = (unsigned short*)(ws + oHb);
        unsigned short* Htb   = (unsigned short*)(ws + oHtb);
        unsigned short* Wb    = (unsigned short*)(ws + oWb);
        unsigned short* QWb   = (unsigned short*)(ws + oQWb);
        unsigned short* Q1wb  = QWb;                 // [118][320]
        unsigned short* Q2wb  = QWb + 118ll*320;     // [8929][320]
        unsigned short* Q12wb = (unsigned short*)(ws + oQ12wb);
        unsigned short* QEb   = (unsigned short*)(ws + oQEb);
        unsigned short* Q1b   = QEb;                 // [118][512]
        unsigned short* Embb  = QEb + 118ll*512;     // [8929][512]
        unsigned short* E1x   = (unsigned short*)(ws + oE1x);
        unsigned short* C1tb  = (unsigned short*)(ws + oC1tb);
        unsigned short* Q2b   = (unsigned short*)(ws + oQ2b);
        unsigned short* A2b   = (unsigned short*)(ws + oA2b);
        float*          part  = (float*)(ws + oPart);
        float*          part1 = (float*)(ws + oPart1);
        float*          invs  = (float*)(ws + oInvs);
        float*          invs1 = (float*)(ws + oInvs1);
        float*          Hsum  = (float*)(ws + oHsum);
        float*          hpart = (float*)(ws + oHpart);

        // 0. all input prep in ONE launch
        mega_prep<<<dim3(18464), blk, 0, stream>>>(H, Hb, Htb, hpart,
                                                   Wmap, Wb, Q1w, Q1wb, Q2w, Q2wb, Q12w, Q12wb);
        reduce_hsum<<<dim3(16), blk, 0, stream>>>(hpart, Hsum);

        // 1+2. [Q1b|Embb] = bf16([Q1wb|Q2wb] @ Wb^T + bmap)   [9047,512] merged
        gemm_mfma_p<5><<<dim3(142), dim3(512), 0, stream>>>(
            QWb, 320, 0, Wb, 320, 0, QEb, 512, 0, 9047, 512, 2, 71, 10,
            bmap, nullptr, 0, nullptr, 0, nullptr, nullptr, nullptr, nullptr);
        // 3. E1x[b] = bf16(expm1(Q1b @ Htb^T)), level-1 row partials
        gemm_mfma_p<16><<<dim3(64), dim3(512), 0, stream>>>(
            Q1b, 512, 0, Htb, 512, 2048*512, E1x, 2048, 128*2048, 118, 2048, 8, 1, 16,
            nullptr, nullptr, 0, part1, 944, nullptr, nullptr, nullptr, nullptr);
        // 4. invs1 = 1/(2000 + sum part1)
        invs_k<<<dim3(4), blk, 0, stream>>>(part1, 944, invs1, 944, 8);
        // 5. C1tb[b] = bf16( ((E1x @ Hb^T + Hsum)*invs1)^T )   [8,512,128]
        gemm_mfma_p<40><<<dim3(16), dim3(512), 0, stream>>>(
            E1x, 2048, 128*2048, Hb, 2048, 512*2048, C1tb, 128, 512*128, 118, 512, 2, 1, 64,
            nullptr, nullptr, 0, nullptr, 0, Hsum, invs1, nullptr, nullptr);
        // 6. Q2b[b] = bf16((Q12wb @ C1tb^T) * Embb)         [8,8929,512]
        gemm_mfma_p<132><<<dim3(1120), dim3(512), 0, stream>>>(
            Q12wb, 128, 0, C1tb, 128, 512*128, Q2b, 512, N2*D, 8929, 512, 2, 70, 4,
            nullptr, (const float*)Embb, 512, nullptr, 0, nullptr, nullptr, nullptr, nullptr);
        // 7. A2b = bf16(expm1(Q2b @ Htb^T)), level-2 row partials
        gemm_mfma_p<16><<<dim3(4480), dim3(512), 0, stream>>>(
            Q2b, 512, N2*D, Htb, 512, 2048*512, A2b, 2048, N2*2048, 8929, 2048, 8, 70, 16,
            nullptr, nullptr, 0, part, 8ll*8929, nullptr, nullptr, nullptr, nullptr);
        // 8. invs = 1/(2000 + sum partials)
        invs_k<<<dim3(280), blk, 0, stream>>>(part, 8ll*8929, invs, (int)(B*N2), 8);
        // 9. C2[b] = (A2b @ Hb^T + Hsum) * invs  +  fused A2 write (nx==0)
        gemm_mfma_p<96><<<dim3(1120), dim3(512), 0, stream>>>(
            A2b, 2048, N2*2048, Hb, 2048, 512*2048, C2, 512, N2*D, 8929, 512, 2, 70, 64,
            nullptr, nullptr, 0, nullptr, 0, Hsum, invs, A2, part);
        return;
    }

    // ---------------- fallback paths ----------------
    float* Q1  = A2;
    float* emb = Q1  + N1*D;
    float* E1  = emb + N2*D;
    float* C1  = E1  + B*N1*L;

    gemm_f32<64,64,4,4,true,true,true,false><<<dim3(8,2,1), blk, 0, stream>>>(
        Q1w, 300, 0, Wmap, 300, 0, Q1, 512, 0, (int)N1, (int)D, 300, bmap, nullptr, 0);
    gemm_f32<64,64,4,4,true,true,true,false><<<dim3(8,140,1), blk, 0, stream>>>(
        Q2w, 300, 0, Wmap, 300, 0, emb, 512, 0, (int)N2, (int)D, 300, bmap, nullptr, 0);
    gemm_f32<64,64,4,4,false,true,true,false><<<dim3(32,2,8), blk, 0, stream>>>(
        Q1, 512, 0, H, 2000, D*L, E1, 2000, N1*L, (int)N1, (int)L, (int)D, nullptr, nullptr, 0);
    softmax_rows<<<dim3((unsigned)(B*N1)), blk, 0, stream>>>(E1, (int)L, nullptr, 0);
    gemm_f32<64,64,4,4,true,true,true,false><<<dim3(8,2,8), blk, 0, stream>>>(
        E1, 2000, N1*L, H, 2000, D*L, C1, 512, N1*D, (int)N1, (int)D, (int)L, nullptr, nullptr, 0);

    constexpr long long HBE = 8ll*512*2048;
    if (ws_size >= (size_t)(2*HBE*sizeof(unsigned short))) {
        unsigned short* Hb  = (unsigned short*)d_ws;
        unsigned short* Htb = Hb + HBE;
        cvt_pad_bf16<<<dim3(4096), blk, 0, stream>>>(H, Hb);
        cvt_transpose_bf16<<<dim3(32,8,8), blk, 0, stream>>>(H, Htb);
        unsigned short* Q2b = (unsigned short*)C2;
        gemm_f32<64,64,4,4,false,false,true,true><<<dim3(8,140,8), blk, 0, stream>>>(
            Q12w, 118, 0, C1, 512, N1*D, Q2b, 512, N2*D, (int)N2, (int)D, (int)N1, nullptr, emb, 512);
        gemm_mfma_p<0><<<dim3(4480), dim3(512), 0, stream>>>(
            Q2b, 512, N2*D, Htb, 512, 2048*512, A2, 2000, N2*L, (int)N2, (int)L, 8, 70, 16,
            nullptr, nullptr, 0, nullptr, 0, nullptr, nullptr, nullptr, nullptr);
        softmax_rows<<<dim3((unsigned)(B*N2)), blk, 0, stream>>>(A2, (int)L, nullptr, 0);
        gemm_mfma<true><<<dim3(2,70,8), dim3(512), 0, stream>>>(
            A2, 2000, N2*L, Hb, 2048, 512*2048, C2, 512, N2*D,
            (int)N2, (int)D, 2000, 63);
    } else {
        float* Q2 = C2;
        gemm_f32<64,64,4,4,false,false,true,false><<<dim3(8,140,8), blk, 0, stream>>>(
            Q12w, 118, 0, C1, 512, N1*D, Q2, 512, N2*D, (int)N2, (int)D, (int)N1, nullptr, emb, 512);
        gemm_f32<128,128,8,8,false,true,true,false><<<dim3(16,70,8), blk, 0, stream>>>(
            Q2, 512, N2*D, H, 2000, D*L, A2, 2000, N2*L, (int)N2, (int)L, (int)D, nullptr, nullptr, 0);
        softmax_rows<<<dim3((unsigned)(B*N2)), blk, 0, stream>>>(A2, (int)L, nullptr, 0);
        gemm_f32<128,128,8,8,true,true,true,false><<<dim3(4,70,8), blk, 0, stream>>>(
            A2, 2000, N2*L, H, 2000, D*L, C2, 512, N2*D, (int)N2, (int)D, (int)L, nullptr, nullptr, 0);
    }
}